// Round 8
// baseline (417.534 us; speedup 1.0000x reference)
//
#include <hip/hip_runtime.h>

// LSH attention, B=4, T=4096, D=512, H=8 hashes, 64 buckets/hash, bucket size 64.
// Round 8: (a) attn_mfma LDS 74->41 KB (V^T and output bounce share the Q buffer)
// -> 3 blocks/CU; (b) GEMM staging via global_load_lds width=16 with pre-swizzled
// per-lane global source (linear LDS dest, swizzled reads unchanged).

typedef __attribute__((ext_vector_type(8))) short short8;
typedef __attribute__((ext_vector_type(4))) float f32x4;
typedef unsigned short ushort_t;

__device__ __forceinline__ ushort_t f2b(float f) {
  union { float f; unsigned u; } x; x.f = f;
  unsigned r = x.u + 0x7fffu + ((x.u >> 16) & 1u);
  return (ushort_t)(r >> 16);
}
__device__ __forceinline__ float b2f(unsigned b) {
  union { unsigned u; float f; } x; x.u = b << 16;
  return x.f;
}
__device__ __forceinline__ void gload16(void* lds, const void* gp) {
  __builtin_amdgcn_global_load_lds(
      (const __attribute__((address_space(1))) unsigned int*)gp,
      (__attribute__((address_space(3))) unsigned int*)lds, 16, 0, 0);
}

// -------- split x into bf16 hi/lo (8 elems/thread) --------
__global__ __launch_bounds__(256) void split_x(
    const float* __restrict__ src, ushort_t* __restrict__ xh,
    ushort_t* __restrict__ xl, int n8)
{
  const int i = blockIdx.x * 256 + threadIdx.x;
  if (i >= n8) return;
  const float4 a = *(const float4*)(src + (size_t)i * 8);
  const float4 c = *(const float4*)(src + (size_t)i * 8 + 4);
  float v[8] = { a.x, a.y, a.z, a.w, c.x, c.y, c.z, c.w };
  ushort_t hi[8], lo[8];
  #pragma unroll
  for (int k = 0; k < 8; ++k) {
    hi[k] = f2b(v[k]);
    lo[k] = f2b(v[k] - b2f(hi[k]));
  }
  *(uint4*)(xh + (size_t)i * 8) = *(const uint4*)hi;
  *(uint4*)(xl + (size_t)i * 8) = *(const uint4*)lo;
}

// ---- transpose + bf16 cvt: Wt[n][k] = bf16(W[k][n]), 512x512 ----
__global__ __launch_bounds__(256) void transpose_cvt(
    const float* __restrict__ W, ushort_t* __restrict__ Wt)
{
  __shared__ float t[32][33];
  const int bx = blockIdx.x * 32, by = blockIdx.y * 32;
  const int tx = threadIdx.x & 31, ty = threadIdx.x >> 5;
  #pragma unroll
  for (int j = 0; j < 4; ++j)
    t[ty + j*8][tx] = W[(size_t)(by + ty + j*8) * 512 + bx + tx];
  __syncthreads();
  #pragma unroll
  for (int j = 0; j < 4; ++j)
    Wt[(size_t)(bx + ty + j*8) * 512 + by + tx] = f2b(t[tx][ty + j*8]);
}

// ---- W2T split: W2Th/W2Tl[j][e] = split(sum_f w_qk[e][f] R[f][j]); b2 = b_qk @ R ----
__global__ __launch_bounds__(256) void w2_split(
    const float* __restrict__ w_qk, const float* __restrict__ b_qk,
    const float* __restrict__ R,
    ushort_t* __restrict__ W2Th, ushort_t* __restrict__ W2Tl, float* __restrict__ b2)
{
  __shared__ float wrow[512];
  const int e = blockIdx.x, j = threadIdx.x;    // j in [0,256)
  const float* src = (e < 512) ? (w_qk + (size_t)e * 512) : b_qk;
  wrow[j]       = src[j];
  wrow[j + 256] = src[j + 256];
  __syncthreads();
  float acc = 0.f;
  for (int f = 0; f < 512; ++f)
    acc = fmaf(wrow[f], R[(size_t)f * 256 + j], acc);
  if (e < 512) {
    const ushort_t hi = f2b(acc);
    W2Th[(size_t)j * 512 + e] = hi;
    W2Tl[(size_t)j * 512 + e] = f2b(acc - b2f(hi));
  } else {
    b2[j] = acc;
  }
}

// ---- bf16 MFMA GEMM (1 product): C = A @ Wt^T + bias ----
__global__ __launch_bounds__(256, 3) void gemm_mfma(
    const ushort_t* __restrict__ A, const ushort_t* __restrict__ Wt,
    const float* __restrict__ bias, float* __restrict__ Cf,
    ushort_t* __restrict__ Cb, int out_bf16)
{
  __shared__ __align__(16) char Al[16384];
  __shared__ __align__(16) char Bl[16384];
  const int bm = blockIdx.x * 128, bn = blockIdx.y * 128;
  const int tid = threadIdx.x, w = tid >> 6, l = tid & 63;
  const int m = l & 15, gq = l >> 4;
  f32x4 acc[2][8] = {};
  for (int k0 = 0; k0 < 512; k0 += 64) {
    #pragma unroll
    for (int j = 0; j < 4; ++j) {
      const int row = w * 32 + j * 8 + (l >> 3);
      const int ch = (l & 7) ^ (row & 7);
      gload16(Al + w * 4096 + j * 1024 + l * 16, A  + (size_t)(bm + row) * 512 + k0 + ch * 8);
      gload16(Bl + w * 4096 + j * 1024 + l * 16, Wt + (size_t)(bn + row) * 512 + k0 + ch * 8);
    }
    __syncthreads();
    #pragma unroll
    for (int ks = 0; ks < 2; ++ks) {
      short8 bfr[8];
      #pragma unroll
      for (int tj = 0; tj < 8; ++tj) {
        const int brow = tj * 16 + m;
        bfr[tj] = *(const short8*)(Bl + ((brow * 128 + ks * 64 + gq * 16) ^ ((brow & 7) << 4)));
      }
      #pragma unroll
      for (int ti = 0; ti < 2; ++ti) {
        const int arow = w * 32 + ti * 16 + m;
        const short8 af = *(const short8*)(Al + ((arow * 128 + ks * 64 + gq * 16) ^ ((arow & 7) << 4)));
        #pragma unroll
        for (int tj = 0; tj < 8; ++tj)
          acc[ti][tj] = __builtin_amdgcn_mfma_f32_16x16x32_bf16(af, bfr[tj], acc[ti][tj], 0, 0, 0);
      }
    }
    __syncthreads();
  }
  #pragma unroll
  for (int ti = 0; ti < 2; ++ti)
    #pragma unroll
    for (int tj = 0; tj < 8; ++tj) {
      const int col = bn + tj * 16 + m;
      const float bvv = bias[col];
      #pragma unroll
      for (int r2 = 0; r2 < 4; ++r2) {
        const int row = bm + w * 32 + ti * 16 + gq * 4 + r2;
        const float oo = acc[ti][tj][r2] + bvv;
        if (out_bf16) Cb[(size_t)row * 512 + col] = f2b(oo);
        else          Cf[(size_t)row * 512 + col] = oo;
      }
    }
}

// ---- bf16 MFMA GEMM (2 A-products): C = (Ah+Al) @ Wt^T + bias -> bf16 ----
__global__ __launch_bounds__(256, 3) void gemm_mfma_x2(
    const ushort_t* __restrict__ Ah, const ushort_t* __restrict__ Al,
    const ushort_t* __restrict__ Wt, const float* __restrict__ bias,
    ushort_t* __restrict__ Cb)
{
  __shared__ __align__(16) char AH[16384], AL[16384], BH[16384];
  const int bm = blockIdx.x * 128, bn = blockIdx.y * 128;
  const int tid = threadIdx.x, w = tid >> 6, l = tid & 63;
  const int m = l & 15, gq = l >> 4;
  f32x4 acc[2][8] = {};
  for (int k0 = 0; k0 < 512; k0 += 64) {
    #pragma unroll
    for (int j = 0; j < 4; ++j) {
      const int row = w * 32 + j * 8 + (l >> 3);
      const int ch = (l & 7) ^ (row & 7);
      const int dst = w * 4096 + j * 1024 + l * 16;
      gload16(AH + dst, Ah + (size_t)(bm + row) * 512 + k0 + ch * 8);
      gload16(AL + dst, Al + (size_t)(bm + row) * 512 + k0 + ch * 8);
      gload16(BH + dst, Wt + (size_t)(bn + row) * 512 + k0 + ch * 8);
    }
    __syncthreads();
    #pragma unroll
    for (int ks = 0; ks < 2; ++ks) {
      short8 bfr[8];
      #pragma unroll
      for (int tj = 0; tj < 8; ++tj) {
        const int brow = tj * 16 + m;
        bfr[tj] = *(const short8*)(BH + ((brow * 128 + ks * 64 + gq * 16) ^ ((brow & 7) << 4)));
      }
      #pragma unroll
      for (int ti = 0; ti < 2; ++ti) {
        const int arow = w * 32 + ti * 16 + m;
        const int aa = (arow * 128 + ks * 64 + gq * 16) ^ ((arow & 7) << 4);
        const short8 ah8 = *(const short8*)(AH + aa);
        const short8 al8 = *(const short8*)(AL + aa);
        #pragma unroll
        for (int tj = 0; tj < 8; ++tj) {
          acc[ti][tj] = __builtin_amdgcn_mfma_f32_16x16x32_bf16(ah8, bfr[tj], acc[ti][tj], 0, 0, 0);
          acc[ti][tj] = __builtin_amdgcn_mfma_f32_16x16x32_bf16(al8, bfr[tj], acc[ti][tj], 0, 0, 0);
        }
      }
    }
    __syncthreads();
  }
  #pragma unroll
  for (int ti = 0; ti < 2; ++ti)
    #pragma unroll
    for (int tj = 0; tj < 8; ++tj) {
      const int col = bn + tj * 16 + m;
      const float bvv = bias[col];
      #pragma unroll
      for (int r2 = 0; r2 < 4; ++r2) {
        const int row = bm + w * 32 + ti * 16 + gq * 4 + r2;
        Cb[(size_t)row * 512 + col] = f2b(acc[ti][tj][r2] + bvv);
      }
    }
}

// ---- rot = (xh+xl)@(W2h+W2l)^T + b2 via 3 MFMA products (lo*lo dropped), fp32 ----
__global__ __launch_bounds__(256, 2) void rot3_mfma(
    const ushort_t* __restrict__ Ah, const ushort_t* __restrict__ Al,
    const ushort_t* __restrict__ Bh, const ushort_t* __restrict__ Bl,
    const float* __restrict__ b2, float* __restrict__ rot)
{
  __shared__ __align__(16) char AH[16384], AL[16384], BH[16384], BL[16384];
  const int bm = blockIdx.x * 128, bn = blockIdx.y * 128;
  const int tid = threadIdx.x, w = tid >> 6, l = tid & 63;
  const int m = l & 15, gq = l >> 4;
  f32x4 acc[2][8] = {};
  for (int k0 = 0; k0 < 512; k0 += 64) {
    #pragma unroll
    for (int j = 0; j < 4; ++j) {
      const int row = w * 32 + j * 8 + (l >> 3);
      const int ch = (l & 7) ^ (row & 7);
      const int dst = w * 4096 + j * 1024 + l * 16;
      gload16(AH + dst, Ah + (size_t)(bm + row) * 512 + k0 + ch * 8);
      gload16(AL + dst, Al + (size_t)(bm + row) * 512 + k0 + ch * 8);
      gload16(BH + dst, Bh + (size_t)(bn + row) * 512 + k0 + ch * 8);
      gload16(BL + dst, Bl + (size_t)(bn + row) * 512 + k0 + ch * 8);
    }
    __syncthreads();
    #pragma unroll
    for (int ks = 0; ks < 2; ++ks) {
      short8 bh8[8], bl8[8];
      #pragma unroll
      for (int tj = 0; tj < 8; ++tj) {
        const int ba = ((tj * 16 + m) * 128 + ks * 64 + gq * 16) ^ (((tj * 16 + m) & 7) << 4);
        bh8[tj] = *(const short8*)(BH + ba);
        bl8[tj] = *(const short8*)(BL + ba);
      }
      #pragma unroll
      for (int ti = 0; ti < 2; ++ti) {
        const int arow = w * 32 + ti * 16 + m;
        const int aa = (arow * 128 + ks * 64 + gq * 16) ^ ((arow & 7) << 4);
        const short8 ah8 = *(const short8*)(AH + aa);
        const short8 al8 = *(const short8*)(AL + aa);
        #pragma unroll
        for (int tj = 0; tj < 8; ++tj) {
          acc[ti][tj] = __builtin_amdgcn_mfma_f32_16x16x32_bf16(ah8, bh8[tj], acc[ti][tj], 0, 0, 0);
          acc[ti][tj] = __builtin_amdgcn_mfma_f32_16x16x32_bf16(al8, bh8[tj], acc[ti][tj], 0, 0, 0);
          acc[ti][tj] = __builtin_amdgcn_mfma_f32_16x16x32_bf16(ah8, bl8[tj], acc[ti][tj], 0, 0, 0);
        }
      }
    }
    __syncthreads();
  }
  #pragma unroll
  for (int ti = 0; ti < 2; ++ti)
    #pragma unroll
    for (int tj = 0; tj < 8; ++tj) {
      const int col = bn + tj * 16 + m;
      const float bvv = b2[col];
      #pragma unroll
      for (int r2 = 0; r2 < 4; ++r2) {
        const int row = bm + w * 32 + ti * 16 + gq * 4 + r2;
        rot[(size_t)row * 256 + col] = acc[ti][tj][r2] + bvv;
      }
    }
}

// ---- argmax over [rot,-rot] + top2 margin; marginal pairs appended to mlist ----
__global__ __launch_bounds__(256) void argmax_margin(
    const float* __restrict__ rot, int* __restrict__ buckets,
    int* __restrict__ mlist, int* __restrict__ mcount, float tau)
{
  const int tok = blockIdx.x;
  const int j = threadIdx.x;             // j = h*32 + i
  const float r = rot[(size_t)tok * 256 + j];
  float m1, m2; int i1;
  if (r >= 0.f) { m1 = r;  i1 = j & 31;        m2 = -r; }
  else          { m1 = -r; i1 = (j & 31) + 32; m2 = r;  }
  #pragma unroll
  for (int off = 16; off; off >>= 1) {
    const float om1 = __shfl_xor(m1, off);
    const int   oi1 = __shfl_xor(i1, off);
    const float om2 = __shfl_xor(m2, off);
    float loser;
    if (om1 > m1 || (om1 == m1 && oi1 < i1)) { loser = m1; m1 = om1; i1 = oi1; }
    else loser = om1;
    m2 = fmaxf(fmaxf(m2, om2), loser);
  }
  if ((j & 31) == 0) {
    const int h = j >> 5, b = tok >> 12, t = tok & 4095;
    buckets[((b << 3) + h) * 4096 + t] = i1;
    if (m1 - m2 < tau) {
      const int k = atomicAdd(mcount, 1);
      mlist[k] = (((b << 3) + h) << 12) | t;
    }
  }
}

// ---- exact np-chain fallback for marginal (b,h,t) pairs ----
__global__ __launch_bounds__(512) void bucket_fallback(
    const float* __restrict__ x, const float* __restrict__ w_qk,
    const float* __restrict__ b_qk, const float* __restrict__ R,
    const int* __restrict__ mlist, const int* __restrict__ mcount,
    int* __restrict__ buckets)
{
  __shared__ float qkrow[512];
  const int n = mcount[0];
  for (int ii = blockIdx.x; ii < n; ii += gridDim.x) {
    const int mm = mlist[ii];
    const int bh = mm >> 12, t = mm & 4095;
    const int b = bh >> 3, h = bh & 7;
    const float* xr = x + ((size_t)b * 4096 + t) * 512;
    {
      const int c = threadIdx.x;
      float a0 = 0.f;
      for (int f = 0; f < 512; ++f) a0 = fmaf(xr[f], w_qk[(size_t)f * 512 + c], a0);
      qkrow[c] = a0 + b_qk[c];
    }
    __syncthreads();
    if (threadIdx.x < 32) {
      const int col = h * 32 + threadIdx.x;
      float a0 = 0.f;
      for (int f = 0; f < 512; ++f) a0 = fmaf(qkrow[f], R[(size_t)f * 256 + col], a0);
      float m1; int i1;
      if (a0 >= 0.f) { m1 = a0;  i1 = threadIdx.x; }
      else           { m1 = -a0; i1 = threadIdx.x + 32; }
      #pragma unroll
      for (int off = 16; off; off >>= 1) {
        const float om = __shfl_xor(m1, off);
        const int   oi = __shfl_xor(i1, off);
        if (om > m1 || (om == m1 && oi < i1)) { m1 = om; i1 = oi; }
      }
      if (threadIdx.x == 0) buckets[(size_t)bh * 4096 + t] = i1;
    }
    __syncthreads();
  }
}

// -------- stable counting sort per (b,h): tokens by (bucket, t) --------
__global__ __launch_bounds__(256) void sort_kernel(
    const int* __restrict__ buckets, int* __restrict__ st)
{
  __shared__ int bk_lds[4096];
  __shared__ int cnt[4][64];
  __shared__ int startq[4][64];
  const int tid = threadIdx.x;
  const int base = blockIdx.x * 4096;     // blockIdx = b*8+h
  for (int t = tid; t < 4096; t += 256) bk_lds[t] = buckets[base + t];
  __syncthreads();
  const int wave = tid >> 6, lane = tid & 63;
  const int q0 = wave * 1024;
  int c = 0;
  for (int t = 0; t < 1024; ++t) c += (bk_lds[q0 + t] == lane);
  cnt[wave][lane] = c;
  __syncthreads();
  if (tid < 64) {
    const int c0 = cnt[0][tid], c1 = cnt[1][tid], c2 = cnt[2][tid], c3 = cnt[3][tid];
    const int tot = c0 + c1 + c2 + c3;
    int ex = tot;
    #pragma unroll
    for (int off = 1; off < 64; off <<= 1) {
      const int nn = __shfl_up(ex, off);
      if (lane >= off) ex += nn;
    }
    const int bucket_start = ex - tot;
    startq[0][tid] = bucket_start;
    startq[1][tid] = bucket_start + c0;
    startq[2][tid] = bucket_start + c0 + c1;
    startq[3][tid] = bucket_start + c0 + c1 + c2;
  }
  __syncthreads();
  int cur = startq[wave][lane];
  for (int t = 0; t < 1024; ++t) {
    if (bk_lds[q0 + t] == lane) { st[base + cur] = q0 + t; cur++; }
  }
}

// -------- scale[token] = D^-0.5 / max(||qk_hi row||, 1e-12) --------
__global__ __launch_bounds__(256) void scale_kernel(
    const ushort_t* __restrict__ qh, float* __restrict__ scale)
{
  const int wave = threadIdx.x >> 6, lane = threadIdx.x & 63;
  const int tok = blockIdx.x * 4 + wave;
  const uint4 H = *(const uint4*)(qh + (size_t)tok * 512 + lane * 8);
  const unsigned* hp = (const unsigned*)&H;
  float s = 0.f;
  #pragma unroll
  for (int e = 0; e < 4; ++e) {
    const float v0 = b2f(hp[e] & 0xffffu);
    const float v1 = b2f(hp[e] >> 16);
    s += v0 * v0 + v1 * v1;
  }
  #pragma unroll
  for (int off = 32; off; off >>= 1) s += __shfl_down(s, off);
  if (lane == 0) {
    const float nn = fmaxf(sqrtf(s), 1e-12f);
    scale[tok] = 0.044194173824159216f / nn;   // 512^-0.5 / norm
  }
}

// -------- MFMA chunked attention: 41 KB LDS (V^T/output share the Q buffer) --------
__global__ __launch_bounds__(256, 3) void attn_mfma(
    const ushort_t* __restrict__ qk_b, const ushort_t* __restrict__ v_b,
    const float* __restrict__ scale, const int* __restrict__ st,
    ushort_t* __restrict__ so, int g, int hbase)
{
  __shared__ __align__(16) char Q[32768];   // qk tiles, then V^T half, then out bounce
  __shared__ __align__(16) char P[8192];    // 64 x 64 bf16
  __shared__ int   stt[64];
  __shared__ float scl[64];

  const int blk = blockIdx.x;
  const int cpg = g * 64;
  const int b = blk / cpg, rem = blk % cpg;
  const int hl = rem >> 6, c = rem & 63;
  const int tid = threadIdx.x, w = tid >> 6, l = tid & 63;
  const int m = l & 15, gq = l >> 4;

  if (tid < 64) {
    const int s = st[(size_t)((b * 8 + hbase + hl) * 4096) + c * 64 + tid];
    stt[tid] = s;
    scl[tid] = scale[b * 4096 + s];
  }
  __syncthreads();

  const size_t qkbase = (size_t)b * 4096;
  f32x4 accS[4] = {};

  // ---- S = Q @ Q^T over two 256-wide K halves ----
  for (int half = 0; half < 2; ++half) {
    #pragma unroll
    for (int it = 0; it < 8; ++it) {
      const int blk16 = it * 256 + tid;
      const int row = blk16 >> 5, u = blk16 & 31;
      const uint4 dat = *(const uint4*)(qk_b + (qkbase + stt[row]) * 512 + half * 256 + u * 8);
      *(uint4*)(Q + ((row * 512 + u * 16) ^ ((row & 7) << 4))) = dat;
    }
    __syncthreads();
    #pragma unroll
    for (int kf = 0; kf < 8; ++kf) {
      const int arow = w * 16 + m;
      const short8 af = *(const short8*)(Q + ((arow * 512 + kf * 64 + gq * 16) ^ ((arow & 7) << 4)));
      #pragma unroll
      for (int jt = 0; jt < 4; ++jt) {
        const int brow = jt * 16 + m;
        const short8 bf = *(const short8*)(Q + ((brow * 512 + kf * 64 + gq * 16) ^ ((brow & 7) << 4)));
        accS[jt] = __builtin_amdgcn_mfma_f32_16x16x32_bf16(af, bf, accS[jt], 0, 0, 0);
      }
    }
    __syncthreads();
  }

  // ---- P[i][j] = S[i][j] * scl[j] -> bf16 (P buffer) ----
  #pragma unroll
  for (int jt = 0; jt < 4; ++jt)
    #pragma unroll
    for (int r = 0; r < 4; ++r) {
      const int i = w * 16 + gq * 4 + r;
      const int j = jt * 16 + m;
      *(ushort_t*)(P + ((i * 128 + j * 2) ^ ((i & 7) << 4))) = f2b(accS[jt][r] * scl[j]);
    }

#define STAGE_VT(HALF) { \
    _Pragma("unroll") \
    for (int it = 0; it < 8; ++it) { \
      const int blk16 = it * 256 + tid; \
      const int j = blk16 >> 5, u = blk16 & 31; \
      const uint4 dat = *(const uint4*)(v_b + (qkbase + stt[j]) * 512 + (HALF) * 256 + u * 8); \
      const ushort_t* e = (const ushort_t*)&dat; \
      _Pragma("unroll") \
      for (int ee = 0; ee < 8; ++ee) { \
        const int d = u * 8 + ee; \
        *(ushort_t*)(Q + ((d * 128 + j * 2) ^ (((d ^ (d >> 3)) & 7) << 4))) = e[ee]; \
      } \
    } }

  STAGE_VT(0)
  __syncthreads();   // P + V^T(half0) visible

  // hoist P fragments (same for both halves)
  short8 ap[2];
  #pragma unroll
  for (int kf = 0; kf < 2; ++kf) {
    const int i = w * 16 + m;
    ap[kf] = *(const short8*)(P + ((i * 128 + kf * 64 + gq * 16) ^ ((i & 7) << 4)));
  }

  const size_t sobase = (size_t)(b * g + hl) * 4096;
  for (int half = 0; half < 2; ++half) {
    f32x4 accO[16] = {};
    #pragma unroll
    for (int dt = 0; dt < 16; ++dt) {
      #pragma unroll
      for (int kf = 0; kf < 2; ++kf) {
        const int d = dt * 16 + m;
        const short8 bv = *(const short8*)(Q + ((d * 128 + kf * 64 + gq * 16) ^ (((d ^ (d >> 3)) & 7) << 4)));
        accO[dt] = __builtin_amdgcn_mfma_f32_16x16x32_bf16(ap[kf], bv, accO[dt], 0, 0, 0);
      }
    }
    __syncthreads();   // all V^T reads done; Q free for bounce

    #pragma unroll
    for (int dt = 0; dt < 16; ++dt)
      #pragma unroll
      for (int r = 0; r < 4; ++r) {
        const int i = w * 16 + gq * 4 + r;
        const int dcol = dt * 16 + m;
        *(ushort_t*)(Q + ((i * 512 + dcol * 2) ^ ((i & 7) << 4))) = f2b(accO[dt][r]);
      }
    __syncthreads();

    // coalesced scatter-flush: row -> so[sobase + stt[row]]
    #pragma unroll
    for (int it = 0; it < 8; ++it) {
      const int blk16 = it * 256 + tid;
      const int row = blk16 >> 5, u = blk16 & 31;
      const uint4 dat = *(const uint4*)(Q + ((row * 512 + u * 16) ^ ((row & 7) << 4)));
      *(uint4*)(so + (sobase + stt[row]) * 512 + half * 256 + u * 8) = dat;
    }
    if (half == 0) {
      __syncthreads();   // flush LDS reads done before restaging
      STAGE_VT(1)
      __syncthreads();   // V^T(half1) visible
    }
  }
#undef STAGE_VT
}

// -------- gather: o_b[tok][:] (+)= sum_{hl<g} so[(b*g+hl)*4096 + t][:], bf16 --------
__global__ __launch_bounds__(256) void gather_kernel(
    const ushort_t* __restrict__ so, ushort_t* __restrict__ o_b, int g, int first)
{
  const int tok = blockIdx.x;
  const int b = tok >> 12, t = tok & 4095;
  const int d0 = threadIdx.x * 2;
  ushort_t* dst = o_b + (size_t)tok * 512 + d0;
  float ax = 0.f, ay = 0.f;
  if (!first) {
    const unsigned u = *(const unsigned*)dst;
    ax = b2f(u & 0xffffu); ay = b2f(u >> 16);
  }
  const size_t stride = (size_t)4096 * 512;
  const ushort_t* src = so + ((size_t)(b * g) * 4096 + t) * 512 + d0;
  for (int hlp = 0; hlp < g; ++hlp) {
    const unsigned u = *(const unsigned*)src;
    ax += b2f(u & 0xffffu);
    ay += b2f(u >> 16);
    src += stride;
  }
  *(unsigned*)dst = ((unsigned)f2b(ay) << 16) | (unsigned)f2b(ax);
}

extern "C" void kernel_launch(void* const* d_in, const int* in_sizes, int n_in,
                              void* d_out, int out_size, void* d_ws, size_t ws_size,
                              hipStream_t stream) {
  const float* x         = (const float*)d_in[0];
  const float* rotations = (const float*)d_in[1];
  const float* w_qk      = (const float*)d_in[2];
  const float* b_qk      = (const float*)d_in[3];
  const float* w_v       = (const float*)d_in[4];
  const float* b_v       = (const float*)d_in[5];
  const float* w_out     = (const float*)d_in[6];
  const float* b_out     = (const float*)d_in[7];
  float* out = (float*)d_out;
  char* ws = (char*)d_ws;

  ushort_t* xh      = (ushort_t*)(ws);                  // 16.78 MB
  ushort_t* xl      = (ushort_t*)(ws + 16777216);       // 16.78 MB
  ushort_t* qk_hi   = (ushort_t*)(ws + 33554432);       // 16.78 MB
  ushort_t* v_b     = (ushort_t*)(ws + 50331648);       // 16.78 MB
  float*    rot     = (float*)(ws + 67108864);          // 16.78 MB (dead after fallback)
  ushort_t* o_b     = (ushort_t*)(ws + 67108864);       // alias: lives after gather
  ushort_t* wqkTh   = (ushort_t*)(ws + 83886080);       // 512 KB
  ushort_t* wvT     = (ushort_t*)(ws + 84410368);       // 512 KB
  ushort_t* woT     = (ushort_t*)(ws + 84934656);       // 512 KB
  ushort_t* W2Th    = (ushort_t*)(ws + 85458944);       // 256 KB
  ushort_t* W2Tl    = (ushort_t*)(ws + 85721088);       // 256 KB
  float*    b2      = (float*)(ws + 85983232);          // 1 KB (pad to 4K)
  float*    scale   = (float*)(ws + 85987328);          // 64 KB
  int*      buckets = (int*)(ws + 86052864);            // 512 KB
  int*      st      = (int*)(ws + 86577152);            // 512 KB
  int*      mlist   = (int*)(ws + 87101440);            // 512 KB (cap 131072: can't overflow)
  int*      mcount  = (int*)(ws + 87625728);            // 4 KB
  ushort_t* so      = (ushort_t*)(ws + 87629824);       // g * 16.78 MB
  const size_t so_off = 87629824;

  int g = 1;
  for (int cand = 8; cand >= 1; cand >>= 1)
    if (so_off + (size_t)cand * 16777216ull <= ws_size) { g = cand; break; }

  const dim3 blk256(256);
  hipLaunchKernelGGL(split_x, dim3(4096), blk256, 0, stream, x, xh, xl, 1048576);
  hipLaunchKernelGGL(transpose_cvt, dim3(16, 16), blk256, 0, stream, w_qk, wqkTh);
  hipLaunchKernelGGL(transpose_cvt, dim3(16, 16), blk256, 0, stream, w_v, wvT);
  hipLaunchKernelGGL(transpose_cvt, dim3(16, 16), blk256, 0, stream, w_out, woT);
  hipLaunchKernelGGL(w2_split, dim3(513), blk256, 0, stream, w_qk, b_qk, rotations, W2Th, W2Tl, b2);

  hipLaunchKernelGGL(gemm_mfma_x2, dim3(128, 4), blk256, 0, stream, xh, xl, wqkTh, b_qk, qk_hi);
  hipLaunchKernelGGL(gemm_mfma, dim3(128, 4), blk256, 0, stream, xh, wvT, b_v, (float*)0, v_b, 1);
  hipLaunchKernelGGL(rot3_mfma, dim3(128, 2), blk256, 0, stream, xh, xl, W2Th, W2Tl, b2, rot);

  hipMemsetAsync(mcount, 0, 4, stream);
  hipLaunchKernelGGL(argmax_margin, dim3(16384), blk256, 0, stream, rot, buckets, mlist, mcount, 3e-3f);
  hipLaunchKernelGGL(bucket_fallback, dim3(256), dim3(512), 0, stream,
                     x, w_qk, b_qk, rotations, mlist, mcount, buckets);
  hipLaunchKernelGGL(sort_kernel, dim3(32), blk256, 0, stream, buckets, st);
  hipLaunchKernelGGL(scale_kernel, dim3(4096), blk256, 0, stream, qk_hi, scale);

  const int passes = 8 / g;
  for (int p = 0; p < passes; ++p) {
    const int hbase = p * g;
    hipLaunchKernelGGL(attn_mfma, dim3(4 * g * 64), blk256, 0, stream,
                       qk_hi, v_b, scale, st, so, g, hbase);
    hipLaunchKernelGGL(gather_kernel, dim3(16384), blk256, 0, stream,
                       so, o_b, g, (p == 0) ? 1 : 0);
  }

  hipLaunchKernelGGL(gemm_mfma, dim3(128, 4), blk256, 0, stream, o_b, woT, b_out, out, (ushort_t*)0, 0);
}

// Round 9
// 340.283 us; speedup vs baseline: 1.2270x; 1.2270x over previous
//
#include <hip/hip_runtime.h>

// LSH attention, B=4, T=4096, D=512, H=8 hashes, 64 buckets/hash, bucket size 64.
// Round 9: attn_mfma reverted to the round-7 schedule (74 KB LDS, 2 blocks/CU,
// proven 77 us) + XCD-aware bijective blockIdx swizzle (batch-per-XCD L2
// locality on the gathered qk/v reads). GEMMs keep global_load_lds staging.

typedef __attribute__((ext_vector_type(8))) short short8;
typedef __attribute__((ext_vector_type(4))) float f32x4;
typedef unsigned short ushort_t;

__device__ __forceinline__ ushort_t f2b(float f) {
  union { float f; unsigned u; } x; x.f = f;
  unsigned r = x.u + 0x7fffu + ((x.u >> 16) & 1u);
  return (ushort_t)(r >> 16);
}
__device__ __forceinline__ float b2f(unsigned b) {
  union { unsigned u; float f; } x; x.u = b << 16;
  return x.f;
}
__device__ __forceinline__ void gload16(void* lds, const void* gp) {
  __builtin_amdgcn_global_load_lds(
      (const __attribute__((address_space(1))) unsigned int*)gp,
      (__attribute__((address_space(3))) unsigned int*)lds, 16, 0, 0);
}

// -------- split x into bf16 hi/lo (8 elems/thread) --------
__global__ __launch_bounds__(256) void split_x(
    const float* __restrict__ src, ushort_t* __restrict__ xh,
    ushort_t* __restrict__ xl, int n8)
{
  const int i = blockIdx.x * 256 + threadIdx.x;
  if (i >= n8) return;
  const float4 a = *(const float4*)(src + (size_t)i * 8);
  const float4 c = *(const float4*)(src + (size_t)i * 8 + 4);
  float v[8] = { a.x, a.y, a.z, a.w, c.x, c.y, c.z, c.w };
  ushort_t hi[8], lo[8];
  #pragma unroll
  for (int k = 0; k < 8; ++k) {
    hi[k] = f2b(v[k]);
    lo[k] = f2b(v[k] - b2f(hi[k]));
  }
  *(uint4*)(xh + (size_t)i * 8) = *(const uint4*)hi;
  *(uint4*)(xl + (size_t)i * 8) = *(const uint4*)lo;
}

// ---- transpose + bf16 cvt: Wt[n][k] = bf16(W[k][n]), 512x512 ----
__global__ __launch_bounds__(256) void transpose_cvt(
    const float* __restrict__ W, ushort_t* __restrict__ Wt)
{
  __shared__ float t[32][33];
  const int bx = blockIdx.x * 32, by = blockIdx.y * 32;
  const int tx = threadIdx.x & 31, ty = threadIdx.x >> 5;
  #pragma unroll
  for (int j = 0; j < 4; ++j)
    t[ty + j*8][tx] = W[(size_t)(by + ty + j*8) * 512 + bx + tx];
  __syncthreads();
  #pragma unroll
  for (int j = 0; j < 4; ++j)
    Wt[(size_t)(bx + ty + j*8) * 512 + by + tx] = f2b(t[tx][ty + j*8]);
}

// ---- W2T split: W2Th/W2Tl[j][e] = split(sum_f w_qk[e][f] R[f][j]); b2 = b_qk @ R ----
__global__ __launch_bounds__(256) void w2_split(
    const float* __restrict__ w_qk, const float* __restrict__ b_qk,
    const float* __restrict__ R,
    ushort_t* __restrict__ W2Th, ushort_t* __restrict__ W2Tl, float* __restrict__ b2)
{
  __shared__ float wrow[512];
  const int e = blockIdx.x, j = threadIdx.x;    // j in [0,256)
  const float* src = (e < 512) ? (w_qk + (size_t)e * 512) : b_qk;
  wrow[j]       = src[j];
  wrow[j + 256] = src[j + 256];
  __syncthreads();
  float acc = 0.f;
  for (int f = 0; f < 512; ++f)
    acc = fmaf(wrow[f], R[(size_t)f * 256 + j], acc);
  if (e < 512) {
    const ushort_t hi = f2b(acc);
    W2Th[(size_t)j * 512 + e] = hi;
    W2Tl[(size_t)j * 512 + e] = f2b(acc - b2f(hi));
  } else {
    b2[j] = acc;
  }
}

// ---- bf16 MFMA GEMM (1 product): C = A @ Wt^T + bias ----
__global__ __launch_bounds__(256, 3) void gemm_mfma(
    const ushort_t* __restrict__ A, const ushort_t* __restrict__ Wt,
    const float* __restrict__ bias, float* __restrict__ Cf,
    ushort_t* __restrict__ Cb, int out_bf16)
{
  __shared__ __align__(16) char Al[16384];
  __shared__ __align__(16) char Bl[16384];
  const int bm = blockIdx.x * 128, bn = blockIdx.y * 128;
  const int tid = threadIdx.x, w = tid >> 6, l = tid & 63;
  const int m = l & 15, gq = l >> 4;
  f32x4 acc[2][8] = {};
  for (int k0 = 0; k0 < 512; k0 += 64) {
    #pragma unroll
    for (int j = 0; j < 4; ++j) {
      const int row = w * 32 + j * 8 + (l >> 3);
      const int ch = (l & 7) ^ (row & 7);
      gload16(Al + w * 4096 + j * 1024 + l * 16, A  + (size_t)(bm + row) * 512 + k0 + ch * 8);
      gload16(Bl + w * 4096 + j * 1024 + l * 16, Wt + (size_t)(bn + row) * 512 + k0 + ch * 8);
    }
    __syncthreads();
    #pragma unroll
    for (int ks = 0; ks < 2; ++ks) {
      short8 bfr[8];
      #pragma unroll
      for (int tj = 0; tj < 8; ++tj) {
        const int brow = tj * 16 + m;
        bfr[tj] = *(const short8*)(Bl + ((brow * 128 + ks * 64 + gq * 16) ^ ((brow & 7) << 4)));
      }
      #pragma unroll
      for (int ti = 0; ti < 2; ++ti) {
        const int arow = w * 32 + ti * 16 + m;
        const short8 af = *(const short8*)(Al + ((arow * 128 + ks * 64 + gq * 16) ^ ((arow & 7) << 4)));
        #pragma unroll
        for (int tj = 0; tj < 8; ++tj)
          acc[ti][tj] = __builtin_amdgcn_mfma_f32_16x16x32_bf16(af, bfr[tj], acc[ti][tj], 0, 0, 0);
      }
    }
    __syncthreads();
  }
  #pragma unroll
  for (int ti = 0; ti < 2; ++ti)
    #pragma unroll
    for (int tj = 0; tj < 8; ++tj) {
      const int col = bn + tj * 16 + m;
      const float bvv = bias[col];
      #pragma unroll
      for (int r2 = 0; r2 < 4; ++r2) {
        const int row = bm + w * 32 + ti * 16 + gq * 4 + r2;
        const float oo = acc[ti][tj][r2] + bvv;
        if (out_bf16) Cb[(size_t)row * 512 + col] = f2b(oo);
        else          Cf[(size_t)row * 512 + col] = oo;
      }
    }
}

// ---- bf16 MFMA GEMM (2 A-products): C = (Ah+Al) @ Wt^T + bias -> bf16 ----
__global__ __launch_bounds__(256, 3) void gemm_mfma_x2(
    const ushort_t* __restrict__ Ah, const ushort_t* __restrict__ Al,
    const ushort_t* __restrict__ Wt, const float* __restrict__ bias,
    ushort_t* __restrict__ Cb)
{
  __shared__ __align__(16) char AH[16384], AL[16384], BH[16384];
  const int bm = blockIdx.x * 128, bn = blockIdx.y * 128;
  const int tid = threadIdx.x, w = tid >> 6, l = tid & 63;
  const int m = l & 15, gq = l >> 4;
  f32x4 acc[2][8] = {};
  for (int k0 = 0; k0 < 512; k0 += 64) {
    #pragma unroll
    for (int j = 0; j < 4; ++j) {
      const int row = w * 32 + j * 8 + (l >> 3);
      const int ch = (l & 7) ^ (row & 7);
      const int dst = w * 4096 + j * 1024 + l * 16;
      gload16(AH + dst, Ah + (size_t)(bm + row) * 512 + k0 + ch * 8);
      gload16(AL + dst, Al + (size_t)(bm + row) * 512 + k0 + ch * 8);
      gload16(BH + dst, Wt + (size_t)(bn + row) * 512 + k0 + ch * 8);
    }
    __syncthreads();
    #pragma unroll
    for (int ks = 0; ks < 2; ++ks) {
      short8 bfr[8];
      #pragma unroll
      for (int tj = 0; tj < 8; ++tj) {
        const int brow = tj * 16 + m;
        bfr[tj] = *(const short8*)(BH + ((brow * 128 + ks * 64 + gq * 16) ^ ((brow & 7) << 4)));
      }
      #pragma unroll
      for (int ti = 0; ti < 2; ++ti) {
        const int arow = w * 32 + ti * 16 + m;
        const int aa = (arow * 128 + ks * 64 + gq * 16) ^ ((arow & 7) << 4);
        const short8 ah8 = *(const short8*)(AH + aa);
        const short8 al8 = *(const short8*)(AL + aa);
        #pragma unroll
        for (int tj = 0; tj < 8; ++tj) {
          acc[ti][tj] = __builtin_amdgcn_mfma_f32_16x16x32_bf16(ah8, bfr[tj], acc[ti][tj], 0, 0, 0);
          acc[ti][tj] = __builtin_amdgcn_mfma_f32_16x16x32_bf16(al8, bfr[tj], acc[ti][tj], 0, 0, 0);
        }
      }
    }
    __syncthreads();
  }
  #pragma unroll
  for (int ti = 0; ti < 2; ++ti)
    #pragma unroll
    for (int tj = 0; tj < 8; ++tj) {
      const int col = bn + tj * 16 + m;
      const float bvv = bias[col];
      #pragma unroll
      for (int r2 = 0; r2 < 4; ++r2) {
        const int row = bm + w * 32 + ti * 16 + gq * 4 + r2;
        Cb[(size_t)row * 512 + col] = f2b(acc[ti][tj][r2] + bvv);
      }
    }
}

// ---- rot = (xh+xl)@(W2h+W2l)^T + b2 via 3 MFMA products (lo*lo dropped), fp32 ----
__global__ __launch_bounds__(256, 2) void rot3_mfma(
    const ushort_t* __restrict__ Ah, const ushort_t* __restrict__ Al,
    const ushort_t* __restrict__ Bh, const ushort_t* __restrict__ Bl,
    const float* __restrict__ b2, float* __restrict__ rot)
{
  __shared__ __align__(16) char AH[16384], AL[16384], BH[16384], BL[16384];
  const int bm = blockIdx.x * 128, bn = blockIdx.y * 128;
  const int tid = threadIdx.x, w = tid >> 6, l = tid & 63;
  const int m = l & 15, gq = l >> 4;
  f32x4 acc[2][8] = {};
  for (int k0 = 0; k0 < 512; k0 += 64) {
    #pragma unroll
    for (int j = 0; j < 4; ++j) {
      const int row = w * 32 + j * 8 + (l >> 3);
      const int ch = (l & 7) ^ (row & 7);
      const int dst = w * 4096 + j * 1024 + l * 16;
      gload16(AH + dst, Ah + (size_t)(bm + row) * 512 + k0 + ch * 8);
      gload16(AL + dst, Al + (size_t)(bm + row) * 512 + k0 + ch * 8);
      gload16(BH + dst, Bh + (size_t)(bn + row) * 512 + k0 + ch * 8);
      gload16(BL + dst, Bl + (size_t)(bn + row) * 512 + k0 + ch * 8);
    }
    __syncthreads();
    #pragma unroll
    for (int ks = 0; ks < 2; ++ks) {
      short8 bh8[8], bl8[8];
      #pragma unroll
      for (int tj = 0; tj < 8; ++tj) {
        const int ba = ((tj * 16 + m) * 128 + ks * 64 + gq * 16) ^ (((tj * 16 + m) & 7) << 4);
        bh8[tj] = *(const short8*)(BH + ba);
        bl8[tj] = *(const short8*)(BL + ba);
      }
      #pragma unroll
      for (int ti = 0; ti < 2; ++ti) {
        const int arow = w * 32 + ti * 16 + m;
        const int aa = (arow * 128 + ks * 64 + gq * 16) ^ ((arow & 7) << 4);
        const short8 ah8 = *(const short8*)(AH + aa);
        const short8 al8 = *(const short8*)(AL + aa);
        #pragma unroll
        for (int tj = 0; tj < 8; ++tj) {
          acc[ti][tj] = __builtin_amdgcn_mfma_f32_16x16x32_bf16(ah8, bh8[tj], acc[ti][tj], 0, 0, 0);
          acc[ti][tj] = __builtin_amdgcn_mfma_f32_16x16x32_bf16(al8, bh8[tj], acc[ti][tj], 0, 0, 0);
          acc[ti][tj] = __builtin_amdgcn_mfma_f32_16x16x32_bf16(ah8, bl8[tj], acc[ti][tj], 0, 0, 0);
        }
      }
    }
    __syncthreads();
  }
  #pragma unroll
  for (int ti = 0; ti < 2; ++ti)
    #pragma unroll
    for (int tj = 0; tj < 8; ++tj) {
      const int col = bn + tj * 16 + m;
      const float bvv = b2[col];
      #pragma unroll
      for (int r2 = 0; r2 < 4; ++r2) {
        const int row = bm + w * 32 + ti * 16 + gq * 4 + r2;
        rot[(size_t)row * 256 + col] = acc[ti][tj][r2] + bvv;
      }
    }
}

// ---- argmax over [rot,-rot] + top2 margin; marginal pairs appended to mlist ----
__global__ __launch_bounds__(256) void argmax_margin(
    const float* __restrict__ rot, int* __restrict__ buckets,
    int* __restrict__ mlist, int* __restrict__ mcount, float tau)
{
  const int tok = blockIdx.x;
  const int j = threadIdx.x;             // j = h*32 + i
  const float r = rot[(size_t)tok * 256 + j];
  float m1, m2; int i1;
  if (r >= 0.f) { m1 = r;  i1 = j & 31;        m2 = -r; }
  else          { m1 = -r; i1 = (j & 31) + 32; m2 = r;  }
  #pragma unroll
  for (int off = 16; off; off >>= 1) {
    const float om1 = __shfl_xor(m1, off);
    const int   oi1 = __shfl_xor(i1, off);
    const float om2 = __shfl_xor(m2, off);
    float loser;
    if (om1 > m1 || (om1 == m1 && oi1 < i1)) { loser = m1; m1 = om1; i1 = oi1; }
    else loser = om1;
    m2 = fmaxf(fmaxf(m2, om2), loser);
  }
  if ((j & 31) == 0) {
    const int h = j >> 5, b = tok >> 12, t = tok & 4095;
    buckets[((b << 3) + h) * 4096 + t] = i1;
    if (m1 - m2 < tau) {
      const int k = atomicAdd(mcount, 1);
      mlist[k] = (((b << 3) + h) << 12) | t;
    }
  }
}

// ---- exact np-chain fallback for marginal (b,h,t) pairs ----
__global__ __launch_bounds__(512) void bucket_fallback(
    const float* __restrict__ x, const float* __restrict__ w_qk,
    const float* __restrict__ b_qk, const float* __restrict__ R,
    const int* __restrict__ mlist, const int* __restrict__ mcount,
    int* __restrict__ buckets)
{
  __shared__ float qkrow[512];
  const int n = mcount[0];
  for (int ii = blockIdx.x; ii < n; ii += gridDim.x) {
    const int mm = mlist[ii];
    const int bh = mm >> 12, t = mm & 4095;
    const int b = bh >> 3, h = bh & 7;
    const float* xr = x + ((size_t)b * 4096 + t) * 512;
    {
      const int c = threadIdx.x;
      float a0 = 0.f;
      for (int f = 0; f < 512; ++f) a0 = fmaf(xr[f], w_qk[(size_t)f * 512 + c], a0);
      qkrow[c] = a0 + b_qk[c];
    }
    __syncthreads();
    if (threadIdx.x < 32) {
      const int col = h * 32 + threadIdx.x;
      float a0 = 0.f;
      for (int f = 0; f < 512; ++f) a0 = fmaf(qkrow[f], R[(size_t)f * 256 + col], a0);
      float m1; int i1;
      if (a0 >= 0.f) { m1 = a0;  i1 = threadIdx.x; }
      else           { m1 = -a0; i1 = threadIdx.x + 32; }
      #pragma unroll
      for (int off = 16; off; off >>= 1) {
        const float om = __shfl_xor(m1, off);
        const int   oi = __shfl_xor(i1, off);
        if (om > m1 || (om == m1 && oi < i1)) { m1 = om; i1 = oi; }
      }
      if (threadIdx.x == 0) buckets[(size_t)bh * 4096 + t] = i1;
    }
    __syncthreads();
  }
}

// -------- stable counting sort per (b,h): tokens by (bucket, t) --------
__global__ __launch_bounds__(256) void sort_kernel(
    const int* __restrict__ buckets, int* __restrict__ st)
{
  __shared__ int bk_lds[4096];
  __shared__ int cnt[4][64];
  __shared__ int startq[4][64];
  const int tid = threadIdx.x;
  const int base = blockIdx.x * 4096;     // blockIdx = b*8+h
  for (int t = tid; t < 4096; t += 256) bk_lds[t] = buckets[base + t];
  __syncthreads();
  const int wave = tid >> 6, lane = tid & 63;
  const int q0 = wave * 1024;
  int c = 0;
  for (int t = 0; t < 1024; ++t) c += (bk_lds[q0 + t] == lane);
  cnt[wave][lane] = c;
  __syncthreads();
  if (tid < 64) {
    const int c0 = cnt[0][tid], c1 = cnt[1][tid], c2 = cnt[2][tid], c3 = cnt[3][tid];
    const int tot = c0 + c1 + c2 + c3;
    int ex = tot;
    #pragma unroll
    for (int off = 1; off < 64; off <<= 1) {
      const int nn = __shfl_up(ex, off);
      if (lane >= off) ex += nn;
    }
    const int bucket_start = ex - tot;
    startq[0][tid] = bucket_start;
    startq[1][tid] = bucket_start + c0;
    startq[2][tid] = bucket_start + c0 + c1;
    startq[3][tid] = bucket_start + c0 + c1 + c2;
  }
  __syncthreads();
  int cur = startq[wave][lane];
  for (int t = 0; t < 1024; ++t) {
    if (bk_lds[q0 + t] == lane) { st[base + cur] = q0 + t; cur++; }
  }
}

// -------- scale[token] = D^-0.5 / max(||qk_hi row||, 1e-12) --------
__global__ __launch_bounds__(256) void scale_kernel(
    const ushort_t* __restrict__ qh, float* __restrict__ scale)
{
  const int wave = threadIdx.x >> 6, lane = threadIdx.x & 63;
  const int tok = blockIdx.x * 4 + wave;
  const uint4 H = *(const uint4*)(qh + (size_t)tok * 512 + lane * 8);
  const unsigned* hp = (const unsigned*)&H;
  float s = 0.f;
  #pragma unroll
  for (int e = 0; e < 4; ++e) {
    const float v0 = b2f(hp[e] & 0xffffu);
    const float v1 = b2f(hp[e] >> 16);
    s += v0 * v0 + v1 * v1;
  }
  #pragma unroll
  for (int off = 32; off; off >>= 1) s += __shfl_down(s, off);
  if (lane == 0) {
    const float nn = fmaxf(sqrtf(s), 1e-12f);
    scale[tok] = 0.044194173824159216f / nn;   // 512^-0.5 / norm
  }
}

// -------- MFMA chunked attention (round-7 schedule + XCD-aware swizzle) --------
__global__ __launch_bounds__(256, 2) void attn_mfma(
    const ushort_t* __restrict__ qk_b, const ushort_t* __restrict__ v_b,
    const float* __restrict__ scale, const int* __restrict__ st,
    ushort_t* __restrict__ so, int g, int hbase)
{
  __shared__ __align__(16) char Q[32768];
  __shared__ __align__(16) char VT[32768];
  __shared__ __align__(16) char P[8192];
  __shared__ int   stt[64];
  __shared__ float scl[64];

  // XCD-aware bijective swizzle: launch-index bid -> XCD bid%8; relabel so
  // each XCD owns a contiguous orig-range (same batch -> same L2).
  const int nwg = gridDim.x;               // multiple of 8 for all g in {1,2,4,8}
  const int cpx = nwg >> 3;
  const int bid = blockIdx.x;
  const int blk = (bid & 7) * cpx + (bid >> 3);

  const int cpg = g * 64;
  const int b = blk / cpg, rem = blk % cpg;
  const int hl = rem >> 6, c = rem & 63;
  const int tid = threadIdx.x, w = tid >> 6, l = tid & 63;
  const int m = l & 15, gq = l >> 4;

  if (tid < 64) {
    const int s = st[(size_t)((b * 8 + hbase + hl) * 4096) + c * 64 + tid];
    stt[tid] = s;
    scl[tid] = scale[b * 4096 + s];
  }
  __syncthreads();

  const size_t qkbase = (size_t)b * 4096;
  f32x4 accS[4] = {};

  for (int half = 0; half < 2; ++half) {
    #pragma unroll
    for (int it = 0; it < 8; ++it) {
      const int blk16 = it * 256 + tid;
      const int row = blk16 >> 5, u = blk16 & 31;
      const uint4 dat = *(const uint4*)(qk_b + (qkbase + stt[row]) * 512 + half * 256 + u * 8);
      *(uint4*)(Q + ((row * 512 + u * 16) ^ ((row & 7) << 4))) = dat;
    }
    __syncthreads();
    #pragma unroll
    for (int kf = 0; kf < 8; ++kf) {
      const int arow = w * 16 + m;
      const short8 af = *(const short8*)(Q + ((arow * 512 + kf * 64 + gq * 16) ^ ((arow & 7) << 4)));
      #pragma unroll
      for (int jt = 0; jt < 4; ++jt) {
        const int brow = jt * 16 + m;
        const short8 bf = *(const short8*)(Q + ((brow * 512 + kf * 64 + gq * 16) ^ ((brow & 7) << 4)));
        accS[jt] = __builtin_amdgcn_mfma_f32_16x16x32_bf16(af, bf, accS[jt], 0, 0, 0);
      }
    }
    __syncthreads();
  }

  #pragma unroll
  for (int jt = 0; jt < 4; ++jt)
    #pragma unroll
    for (int r = 0; r < 4; ++r) {
      const int i = w * 16 + gq * 4 + r;
      const int j = jt * 16 + m;
      *(ushort_t*)(P + ((i * 128 + j * 2) ^ ((i & 7) << 4))) = f2b(accS[jt][r] * scl[j]);
    }

  const size_t sobase = (size_t)(b * g + hl) * 4096;
  for (int half = 0; half < 2; ++half) {
    #pragma unroll
    for (int it = 0; it < 8; ++it) {
      const int blk16 = it * 256 + tid;
      const int j = blk16 >> 5, u = blk16 & 31;
      const uint4 dat = *(const uint4*)(v_b + (qkbase + stt[j]) * 512 + half * 256 + u * 8);
      const ushort_t* e = (const ushort_t*)&dat;
      #pragma unroll
      for (int ee = 0; ee < 8; ++ee) {
        const int d = u * 8 + ee;
        *(ushort_t*)(VT + ((d * 128 + j * 2) ^ (((d ^ (d >> 3)) & 7) << 4))) = e[ee];
      }
    }
    __syncthreads();

    short8 ap[2];
    #pragma unroll
    for (int kf = 0; kf < 2; ++kf) {
      const int i = w * 16 + m;
      ap[kf] = *(const short8*)(P + ((i * 128 + kf * 64 + gq * 16) ^ ((i & 7) << 4)));
    }
    f32x4 accO[16] = {};
    #pragma unroll
    for (int dt = 0; dt < 16; ++dt) {
      #pragma unroll
      for (int kf = 0; kf < 2; ++kf) {
        const int d = dt * 16 + m;
        const short8 bv = *(const short8*)(VT + ((d * 128 + kf * 64 + gq * 16) ^ (((d ^ (d >> 3)) & 7) << 4)));
        accO[dt] = __builtin_amdgcn_mfma_f32_16x16x32_bf16(ap[kf], bv, accO[dt], 0, 0, 0);
      }
    }
    __syncthreads();

    #pragma unroll
    for (int dt = 0; dt < 16; ++dt)
      #pragma unroll
      for (int r = 0; r < 4; ++r) {
        const int i = w * 16 + gq * 4 + r;
        const int dcol = dt * 16 + m;
        *(ushort_t*)(Q + ((i * 512 + dcol * 2) ^ ((i & 7) << 4))) = f2b(accO[dt][r]);
      }
    __syncthreads();

    #pragma unroll
    for (int it = 0; it < 8; ++it) {
      const int blk16 = it * 256 + tid;
      const int row = blk16 >> 5, u = blk16 & 31;
      const uint4 dat = *(const uint4*)(Q + ((row * 512 + u * 16) ^ ((row & 7) << 4)));
      *(uint4*)(so + (sobase + stt[row]) * 512 + half * 256 + u * 8) = dat;
    }
  }
}

// -------- gather: o_b[tok][:] (+)= sum_{hl<g} so[(b*g+hl)*4096 + t][:], bf16 --------
__global__ __launch_bounds__(256) void gather_kernel(
    const ushort_t* __restrict__ so, ushort_t* __restrict__ o_b, int g, int first)
{
  const int tok = blockIdx.x;
  const int b = tok >> 12, t = tok & 4095;
  const int d0 = threadIdx.x * 2;
  ushort_t* dst = o_b + (size_t)tok * 512 + d0;
  float ax = 0.f, ay = 0.f;
  if (!first) {
    const unsigned u = *(const unsigned*)dst;
    ax = b2f(u & 0xffffu); ay = b2f(u >> 16);
  }
  const size_t stride = (size_t)4096 * 512;
  const ushort_t* src = so + ((size_t)(b * g) * 4096 + t) * 512 + d0;
  for (int hlp = 0; hlp < g; ++hlp) {
    const unsigned u = *(const unsigned*)src;
    ax += b2f(u & 0xffffu);
    ay += b2f(u >> 16);
    src += stride;
  }
  *(unsigned*)dst = ((unsigned)f2b(ay) << 16) | (unsigned)f2b(ax);
}

extern "C" void kernel_launch(void* const* d_in, const int* in_sizes, int n_in,
                              void* d_out, int out_size, void* d_ws, size_t ws_size,
                              hipStream_t stream) {
  const float* x         = (const float*)d_in[0];
  const float* rotations = (const float*)d_in[1];
  const float* w_qk      = (const float*)d_in[2];
  const float* b_qk      = (const float*)d_in[3];
  const float* w_v       = (const float*)d_in[4];
  const float* b_v       = (const float*)d_in[5];
  const float* w_out     = (const float*)d_in[6];
  const float* b_out     = (const float*)d_in[7];
  float* out = (float*)d_out;
  char* ws = (char*)d_ws;

  ushort_t* xh      = (ushort_t*)(ws);                  // 16.78 MB
  ushort_t* xl      = (ushort_t*)(ws + 16777216);       // 16.78 MB
  ushort_t* qk_hi   = (ushort_t*)(ws + 33554432);       // 16.78 MB
  ushort_t* v_b     = (ushort_t*)(ws + 50331648);       // 16.78 MB
  float*    rot     = (float*)(ws + 67108864);          // 16.78 MB (dead after fallback)
  ushort_t* o_b     = (ushort_t*)(ws + 67108864);       // alias: lives after gather
  ushort_t* wqkTh   = (ushort_t*)(ws + 83886080);       // 512 KB
  ushort_t* wvT     = (ushort_t*)(ws + 84410368);       // 512 KB
  ushort_t* woT     = (ushort_t*)(ws + 84934656);       // 512 KB
  ushort_t* W2Th    = (ushort_t*)(ws + 85458944);       // 256 KB
  ushort_t* W2Tl    = (ushort_t*)(ws + 85721088);       // 256 KB
  float*    b2      = (float*)(ws + 85983232);          // 1 KB (pad to 4K)
  float*    scale   = (float*)(ws + 85987328);          // 64 KB
  int*      buckets = (int*)(ws + 86052864);            // 512 KB
  int*      st      = (int*)(ws + 86577152);            // 512 KB
  int*      mlist   = (int*)(ws + 87101440);            // 512 KB (cap 131072: can't overflow)
  int*      mcount  = (int*)(ws + 87625728);            // 4 KB
  ushort_t* so      = (ushort_t*)(ws + 87629824);       // g * 16.78 MB
  const size_t so_off = 87629824;

  int g = 1;
  for (int cand = 8; cand >= 1; cand >>= 1)
    if (so_off + (size_t)cand * 16777216ull <= ws_size) { g = cand; break; }

  const dim3 blk256(256);
  hipLaunchKernelGGL(split_x, dim3(4096), blk256, 0, stream, x, xh, xl, 1048576);
  hipLaunchKernelGGL(transpose_cvt, dim3(16, 16), blk256, 0, stream, w_qk, wqkTh);
  hipLaunchKernelGGL(transpose_cvt, dim3(16, 16), blk256, 0, stream, w_v, wvT);
  hipLaunchKernelGGL(transpose_cvt, dim3(16, 16), blk256, 0, stream, w_out, woT);
  hipLaunchKernelGGL(w2_split, dim3(513), blk256, 0, stream, w_qk, b_qk, rotations, W2Th, W2Tl, b2);

  hipLaunchKernelGGL(gemm_mfma_x2, dim3(128, 4), blk256, 0, stream, xh, xl, wqkTh, b_qk, qk_hi);
  hipLaunchKernelGGL(gemm_mfma, dim3(128, 4), blk256, 0, stream, xh, wvT, b_v, (float*)0, v_b, 1);
  hipLaunchKernelGGL(rot3_mfma, dim3(128, 2), blk256, 0, stream, xh, xl, W2Th, W2Tl, b2, rot);

  hipMemsetAsync(mcount, 0, 4, stream);
  hipLaunchKernelGGL(argmax_margin, dim3(16384), blk256, 0, stream, rot, buckets, mlist, mcount, 3e-3f);
  hipLaunchKernelGGL(bucket_fallback, dim3(256), dim3(512), 0, stream,
                     x, w_qk, b_qk, rotations, mlist, mcount, buckets);
  hipLaunchKernelGGL(sort_kernel, dim3(32), blk256, 0, stream, buckets, st);
  hipLaunchKernelGGL(scale_kernel, dim3(4096), blk256, 0, stream, qk_hi, scale);

  const int passes = 8 / g;
  for (int p = 0; p < passes; ++p) {
    const int hbase = p * g;
    hipLaunchKernelGGL(attn_mfma, dim3(4 * g * 64), blk256, 0, stream,
                       qk_hi, v_b, scale, st, so, g, hbase);
    hipLaunchKernelGGL(gather_kernel, dim3(16384), blk256, 0, stream,
                       so, o_b, g, (p == 0) ? 1 : 0);
  }

  hipLaunchKernelGGL(gemm_mfma, dim3(128, 4), blk256, 0, stream, o_b, woT, b_out, out, (ushort_t*)0, 0);
}

// Round 10
// 325.199 us; speedup vs baseline: 1.2839x; 1.0464x over previous
//
#include <hip/hip_runtime.h>

// LSH attention, B=4, T=4096, D=512, H=8 hashes, 64 buckets/hash, bucket size 64.
// Round 10: consolidation. (a) XCD swizzle reverted (proved -5us / -44MB FETCH);
// (b) prep fused into one kernel (split_x + 3 transposes + w2_split + mcount=0);
// (c) scale fused into argmax launch; (d) tau 3e-3 -> 1.5e-3, fallback grid 1024.
// 16 -> 10 kernel launches.

typedef __attribute__((ext_vector_type(8))) short short8;
typedef __attribute__((ext_vector_type(4))) float f32x4;
typedef unsigned short ushort_t;

__device__ __forceinline__ ushort_t f2b(float f) {
  union { float f; unsigned u; } x; x.f = f;
  unsigned r = x.u + 0x7fffu + ((x.u >> 16) & 1u);
  return (ushort_t)(r >> 16);
}
__device__ __forceinline__ float b2f(unsigned b) {
  union { unsigned u; float f; } x; x.u = b << 16;
  return x.f;
}
__device__ __forceinline__ void gload16(void* lds, const void* gp) {
  __builtin_amdgcn_global_load_lds(
      (const __attribute__((address_space(1))) unsigned int*)gp,
      (__attribute__((address_space(3))) unsigned int*)lds, 16, 0, 0);
}

// -------- fused prep: split_x | transpose_cvt x3 | w2_split | mcount=0 --------
// grid: [0,4096) split_x; [4096,4864) transposes (256 blocks per matrix);
//       [4864,5377) w2_split row e = blk-4864.
__global__ __launch_bounds__(256) void prep_kernel(
    const float* __restrict__ x, const float* __restrict__ w_qk,
    const float* __restrict__ b_qk, const float* __restrict__ R,
    const float* __restrict__ w_v, const float* __restrict__ w_out,
    ushort_t* __restrict__ xh, ushort_t* __restrict__ xl,
    ushort_t* __restrict__ wqkT, ushort_t* __restrict__ wvT, ushort_t* __restrict__ woT,
    ushort_t* __restrict__ W2Th, ushort_t* __restrict__ W2Tl, float* __restrict__ b2,
    int* __restrict__ mcount)
{
  __shared__ float t[32][33];
  __shared__ float wrow[512];
  const int blk = blockIdx.x, tid = threadIdx.x;
  if (blk == 0 && tid == 0) mcount[0] = 0;

  if (blk < 4096) {                      // ---- split_x ----
    const int i = blk * 256 + tid;
    const float4 a = *(const float4*)(x + (size_t)i * 8);
    const float4 c = *(const float4*)(x + (size_t)i * 8 + 4);
    float v[8] = { a.x, a.y, a.z, a.w, c.x, c.y, c.z, c.w };
    ushort_t hi[8], lo[8];
    #pragma unroll
    for (int k = 0; k < 8; ++k) {
      hi[k] = f2b(v[k]);
      lo[k] = f2b(v[k] - b2f(hi[k]));
    }
    *(uint4*)(xh + (size_t)i * 8) = *(const uint4*)hi;
    *(uint4*)(xl + (size_t)i * 8) = *(const uint4*)lo;
  } else if (blk < 4864) {               // ---- transpose_cvt x3 ----
    const int idx = blk - 4096;
    const int mat = idx >> 8, r = idx & 255;
    const float* W  = (mat == 0) ? w_qk : (mat == 1) ? w_v : w_out;
    ushort_t*   Wt  = (mat == 0) ? wqkT : (mat == 1) ? wvT : woT;
    const int bx = (r & 15) * 32, by = (r >> 4) * 32;
    const int tx = tid & 31, ty = tid >> 5;
    #pragma unroll
    for (int j = 0; j < 4; ++j)
      t[ty + j*8][tx] = W[(size_t)(by + ty + j*8) * 512 + bx + tx];
    __syncthreads();
    #pragma unroll
    for (int j = 0; j < 4; ++j)
      Wt[(size_t)(bx + ty + j*8) * 512 + by + tx] = f2b(t[tx][ty + j*8]);
  } else {                               // ---- w2_split ----
    const int e = blk - 4864, j = tid;   // e in [0,513), j in [0,256)
    const float* src = (e < 512) ? (w_qk + (size_t)e * 512) : b_qk;
    wrow[j]       = src[j];
    wrow[j + 256] = src[j + 256];
    __syncthreads();
    float acc = 0.f;
    for (int f = 0; f < 512; ++f)
      acc = fmaf(wrow[f], R[(size_t)f * 256 + j], acc);
    if (e < 512) {
      const ushort_t hi = f2b(acc);
      W2Th[(size_t)j * 512 + e] = hi;
      W2Tl[(size_t)j * 512 + e] = f2b(acc - b2f(hi));
    } else {
      b2[j] = acc;
    }
  }
}

// ---- bf16 MFMA GEMM (1 product): C = A @ Wt^T + bias ----
__global__ __launch_bounds__(256, 3) void gemm_mfma(
    const ushort_t* __restrict__ A, const ushort_t* __restrict__ Wt,
    const float* __restrict__ bias, float* __restrict__ Cf,
    ushort_t* __restrict__ Cb, int out_bf16)
{
  __shared__ __align__(16) char Al[16384];
  __shared__ __align__(16) char Bl[16384];
  const int bm = blockIdx.x * 128, bn = blockIdx.y * 128;
  const int tid = threadIdx.x, w = tid >> 6, l = tid & 63;
  const int m = l & 15, gq = l >> 4;
  f32x4 acc[2][8] = {};
  for (int k0 = 0; k0 < 512; k0 += 64) {
    #pragma unroll
    for (int j = 0; j < 4; ++j) {
      const int row = w * 32 + j * 8 + (l >> 3);
      const int ch = (l & 7) ^ (row & 7);
      gload16(Al + w * 4096 + j * 1024 + l * 16, A  + (size_t)(bm + row) * 512 + k0 + ch * 8);
      gload16(Bl + w * 4096 + j * 1024 + l * 16, Wt + (size_t)(bn + row) * 512 + k0 + ch * 8);
    }
    __syncthreads();
    #pragma unroll
    for (int ks = 0; ks < 2; ++ks) {
      short8 bfr[8];
      #pragma unroll
      for (int tj = 0; tj < 8; ++tj) {
        const int brow = tj * 16 + m;
        bfr[tj] = *(const short8*)(Bl + ((brow * 128 + ks * 64 + gq * 16) ^ ((brow & 7) << 4)));
      }
      #pragma unroll
      for (int ti = 0; ti < 2; ++ti) {
        const int arow = w * 32 + ti * 16 + m;
        const short8 af = *(const short8*)(Al + ((arow * 128 + ks * 64 + gq * 16) ^ ((arow & 7) << 4)));
        #pragma unroll
        for (int tj = 0; tj < 8; ++tj)
          acc[ti][tj] = __builtin_amdgcn_mfma_f32_16x16x32_bf16(af, bfr[tj], acc[ti][tj], 0, 0, 0);
      }
    }
    __syncthreads();
  }
  #pragma unroll
  for (int ti = 0; ti < 2; ++ti)
    #pragma unroll
    for (int tj = 0; tj < 8; ++tj) {
      const int col = bn + tj * 16 + m;
      const float bvv = bias[col];
      #pragma unroll
      for (int r2 = 0; r2 < 4; ++r2) {
        const int row = bm + w * 32 + ti * 16 + gq * 4 + r2;
        const float oo = acc[ti][tj][r2] + bvv;
        if (out_bf16) Cb[(size_t)row * 512 + col] = f2b(oo);
        else          Cf[(size_t)row * 512 + col] = oo;
      }
    }
}

// ---- bf16 MFMA GEMM (2 A-products): C = (Ah+Al) @ Wt^T + bias -> bf16 ----
__global__ __launch_bounds__(256, 3) void gemm_mfma_x2(
    const ushort_t* __restrict__ Ah, const ushort_t* __restrict__ Al,
    const ushort_t* __restrict__ Wt, const float* __restrict__ bias,
    ushort_t* __restrict__ Cb)
{
  __shared__ __align__(16) char AH[16384], AL[16384], BH[16384];
  const int bm = blockIdx.x * 128, bn = blockIdx.y * 128;
  const int tid = threadIdx.x, w = tid >> 6, l = tid & 63;
  const int m = l & 15, gq = l >> 4;
  f32x4 acc[2][8] = {};
  for (int k0 = 0; k0 < 512; k0 += 64) {
    #pragma unroll
    for (int j = 0; j < 4; ++j) {
      const int row = w * 32 + j * 8 + (l >> 3);
      const int ch = (l & 7) ^ (row & 7);
      const int dst = w * 4096 + j * 1024 + l * 16;
      gload16(AH + dst, Ah + (size_t)(bm + row) * 512 + k0 + ch * 8);
      gload16(AL + dst, Al + (size_t)(bm + row) * 512 + k0 + ch * 8);
      gload16(BH + dst, Wt + (size_t)(bn + row) * 512 + k0 + ch * 8);
    }
    __syncthreads();
    #pragma unroll
    for (int ks = 0; ks < 2; ++ks) {
      short8 bfr[8];
      #pragma unroll
      for (int tj = 0; tj < 8; ++tj) {
        const int brow = tj * 16 + m;
        bfr[tj] = *(const short8*)(BH + ((brow * 128 + ks * 64 + gq * 16) ^ ((brow & 7) << 4)));
      }
      #pragma unroll
      for (int ti = 0; ti < 2; ++ti) {
        const int arow = w * 32 + ti * 16 + m;
        const int aa = (arow * 128 + ks * 64 + gq * 16) ^ ((arow & 7) << 4);
        const short8 ah8 = *(const short8*)(AH + aa);
        const short8 al8 = *(const short8*)(AL + aa);
        #pragma unroll
        for (int tj = 0; tj < 8; ++tj) {
          acc[ti][tj] = __builtin_amdgcn_mfma_f32_16x16x32_bf16(ah8, bfr[tj], acc[ti][tj], 0, 0, 0);
          acc[ti][tj] = __builtin_amdgcn_mfma_f32_16x16x32_bf16(al8, bfr[tj], acc[ti][tj], 0, 0, 0);
        }
      }
    }
    __syncthreads();
  }
  #pragma unroll
  for (int ti = 0; ti < 2; ++ti)
    #pragma unroll
    for (int tj = 0; tj < 8; ++tj) {
      const int col = bn + tj * 16 + m;
      const float bvv = bias[col];
      #pragma unroll
      for (int r2 = 0; r2 < 4; ++r2) {
        const int row = bm + w * 32 + ti * 16 + gq * 4 + r2;
        Cb[(size_t)row * 512 + col] = f2b(acc[ti][tj][r2] + bvv);
      }
    }
}

// ---- rot = (xh+xl)@(W2h+W2l)^T + b2 via 3 MFMA products (lo*lo dropped), fp32 ----
__global__ __launch_bounds__(256, 2) void rot3_mfma(
    const ushort_t* __restrict__ Ah, const ushort_t* __restrict__ Al,
    const ushort_t* __restrict__ Bh, const ushort_t* __restrict__ Bl,
    const float* __restrict__ b2, float* __restrict__ rot)
{
  __shared__ __align__(16) char AH[16384], AL[16384], BH[16384], BL[16384];
  const int bm = blockIdx.x * 128, bn = blockIdx.y * 128;
  const int tid = threadIdx.x, w = tid >> 6, l = tid & 63;
  const int m = l & 15, gq = l >> 4;
  f32x4 acc[2][8] = {};
  for (int k0 = 0; k0 < 512; k0 += 64) {
    #pragma unroll
    for (int j = 0; j < 4; ++j) {
      const int row = w * 32 + j * 8 + (l >> 3);
      const int ch = (l & 7) ^ (row & 7);
      const int dst = w * 4096 + j * 1024 + l * 16;
      gload16(AH + dst, Ah + (size_t)(bm + row) * 512 + k0 + ch * 8);
      gload16(AL + dst, Al + (size_t)(bm + row) * 512 + k0 + ch * 8);
      gload16(BH + dst, Bh + (size_t)(bn + row) * 512 + k0 + ch * 8);
      gload16(BL + dst, Bl + (size_t)(bn + row) * 512 + k0 + ch * 8);
    }
    __syncthreads();
    #pragma unroll
    for (int ks = 0; ks < 2; ++ks) {
      short8 bh8[8], bl8[8];
      #pragma unroll
      for (int tj = 0; tj < 8; ++tj) {
        const int ba = ((tj * 16 + m) * 128 + ks * 64 + gq * 16) ^ (((tj * 16 + m) & 7) << 4);
        bh8[tj] = *(const short8*)(BH + ba);
        bl8[tj] = *(const short8*)(BL + ba);
      }
      #pragma unroll
      for (int ti = 0; ti < 2; ++ti) {
        const int arow = w * 32 + ti * 16 + m;
        const int aa = (arow * 128 + ks * 64 + gq * 16) ^ ((arow & 7) << 4);
        const short8 ah8 = *(const short8*)(AH + aa);
        const short8 al8 = *(const short8*)(AL + aa);
        #pragma unroll
        for (int tj = 0; tj < 8; ++tj) {
          acc[ti][tj] = __builtin_amdgcn_mfma_f32_16x16x32_bf16(ah8, bh8[tj], acc[ti][tj], 0, 0, 0);
          acc[ti][tj] = __builtin_amdgcn_mfma_f32_16x16x32_bf16(al8, bh8[tj], acc[ti][tj], 0, 0, 0);
          acc[ti][tj] = __builtin_amdgcn_mfma_f32_16x16x32_bf16(ah8, bl8[tj], acc[ti][tj], 0, 0, 0);
        }
      }
    }
    __syncthreads();
  }
  #pragma unroll
  for (int ti = 0; ti < 2; ++ti)
    #pragma unroll
    for (int tj = 0; tj < 8; ++tj) {
      const int col = bn + tj * 16 + m;
      const float bvv = b2[col];
      #pragma unroll
      for (int r2 = 0; r2 < 4; ++r2) {
        const int row = bm + w * 32 + ti * 16 + gq * 4 + r2;
        rot[(size_t)row * 256 + col] = acc[ti][tj][r2] + bvv;
      }
    }
}

// ---- fused: argmax+margin (blocks < 16384) | scale (blocks >= 16384) ----
__global__ __launch_bounds__(256) void argmax_scale(
    const float* __restrict__ rot, int* __restrict__ buckets,
    int* __restrict__ mlist, int* __restrict__ mcount, float tau,
    const ushort_t* __restrict__ qh, float* __restrict__ scale)
{
  const int blk = blockIdx.x;
  if (blk < 16384) {
    const int tok = blk;
    const int j = threadIdx.x;             // j = h*32 + i
    const float r = rot[(size_t)tok * 256 + j];
    float m1, m2; int i1;
    if (r >= 0.f) { m1 = r;  i1 = j & 31;        m2 = -r; }
    else          { m1 = -r; i1 = (j & 31) + 32; m2 = r;  }
    #pragma unroll
    for (int off = 16; off; off >>= 1) {
      const float om1 = __shfl_xor(m1, off);
      const int   oi1 = __shfl_xor(i1, off);
      const float om2 = __shfl_xor(m2, off);
      float loser;
      if (om1 > m1 || (om1 == m1 && oi1 < i1)) { loser = m1; m1 = om1; i1 = oi1; }
      else loser = om1;
      m2 = fmaxf(fmaxf(m2, om2), loser);
    }
    if ((j & 31) == 0) {
      const int h = j >> 5, b = tok >> 12, t = tok & 4095;
      buckets[((b << 3) + h) * 4096 + t] = i1;
      if (m1 - m2 < tau) {
        const int k = atomicAdd(mcount, 1);
        mlist[k] = (((b << 3) + h) << 12) | t;
      }
    }
  } else {
    const int wave = threadIdx.x >> 6, lane = threadIdx.x & 63;
    const int tok = (blk - 16384) * 4 + wave;
    const uint4 H = *(const uint4*)(qh + (size_t)tok * 512 + lane * 8);
    const unsigned* hp = (const unsigned*)&H;
    float s = 0.f;
    #pragma unroll
    for (int e = 0; e < 4; ++e) {
      const float v0 = b2f(hp[e] & 0xffffu);
      const float v1 = b2f(hp[e] >> 16);
      s += v0 * v0 + v1 * v1;
    }
    #pragma unroll
    for (int off = 32; off; off >>= 1) s += __shfl_down(s, off);
    if (lane == 0) {
      const float nn = fmaxf(sqrtf(s), 1e-12f);
      scale[tok] = 0.044194173824159216f / nn;   // 512^-0.5 / norm
    }
  }
}

// ---- exact np-chain fallback for marginal (b,h,t) pairs ----
__global__ __launch_bounds__(512) void bucket_fallback(
    const float* __restrict__ x, const float* __restrict__ w_qk,
    const float* __restrict__ b_qk, const float* __restrict__ R,
    const int* __restrict__ mlist, const int* __restrict__ mcount,
    int* __restrict__ buckets)
{
  __shared__ float qkrow[512];
  const int n = mcount[0];
  for (int ii = blockIdx.x; ii < n; ii += gridDim.x) {
    const int mm = mlist[ii];
    const int bh = mm >> 12, t = mm & 4095;
    const int b = bh >> 3, h = bh & 7;
    const float* xr = x + ((size_t)b * 4096 + t) * 512;
    {
      const int c = threadIdx.x;
      float a0 = 0.f;
      for (int f = 0; f < 512; ++f) a0 = fmaf(xr[f], w_qk[(size_t)f * 512 + c], a0);
      qkrow[c] = a0 + b_qk[c];
    }
    __syncthreads();
    if (threadIdx.x < 32) {
      const int col = h * 32 + threadIdx.x;
      float a0 = 0.f;
      for (int f = 0; f < 512; ++f) a0 = fmaf(qkrow[f], R[(size_t)f * 256 + col], a0);
      float m1; int i1;
      if (a0 >= 0.f) { m1 = a0;  i1 = threadIdx.x; }
      else           { m1 = -a0; i1 = threadIdx.x + 32; }
      #pragma unroll
      for (int off = 16; off; off >>= 1) {
        const float om = __shfl_xor(m1, off);
        const int   oi = __shfl_xor(i1, off);
        if (om > m1 || (om == m1 && oi < i1)) { m1 = om; i1 = oi; }
      }
      if (threadIdx.x == 0) buckets[(size_t)bh * 4096 + t] = i1;
    }
    __syncthreads();
  }
}

// -------- stable counting sort per (b,h): tokens by (bucket, t) --------
__global__ __launch_bounds__(256) void sort_kernel(
    const int* __restrict__ buckets, int* __restrict__ st)
{
  __shared__ int bk_lds[4096];
  __shared__ int cnt[4][64];
  __shared__ int startq[4][64];
  const int tid = threadIdx.x;
  const int base = blockIdx.x * 4096;     // blockIdx = b*8+h
  for (int t = tid; t < 4096; t += 256) bk_lds[t] = buckets[base + t];
  __syncthreads();
  const int wave = tid >> 6, lane = tid & 63;
  const int q0 = wave * 1024;
  int c = 0;
  for (int t = 0; t < 1024; ++t) c += (bk_lds[q0 + t] == lane);
  cnt[wave][lane] = c;
  __syncthreads();
  if (tid < 64) {
    const int c0 = cnt[0][tid], c1 = cnt[1][tid], c2 = cnt[2][tid], c3 = cnt[3][tid];
    const int tot = c0 + c1 + c2 + c3;
    int ex = tot;
    #pragma unroll
    for (int off = 1; off < 64; off <<= 1) {
      const int nn = __shfl_up(ex, off);
      if (lane >= off) ex += nn;
    }
    const int bucket_start = ex - tot;
    startq[0][tid] = bucket_start;
    startq[1][tid] = bucket_start + c0;
    startq[2][tid] = bucket_start + c0 + c1;
    startq[3][tid] = bucket_start + c0 + c1 + c2;
  }
  __syncthreads();
  int cur = startq[wave][lane];
  for (int t = 0; t < 1024; ++t) {
    if (bk_lds[q0 + t] == lane) { st[base + cur] = q0 + t; cur++; }
  }
}

// -------- MFMA chunked attention (round-7 schedule, no swizzle) --------
__global__ __launch_bounds__(256, 2) void attn_mfma(
    const ushort_t* __restrict__ qk_b, const ushort_t* __restrict__ v_b,
    const float* __restrict__ scale, const int* __restrict__ st,
    ushort_t* __restrict__ so, int g, int hbase)
{
  __shared__ __align__(16) char Q[32768];
  __shared__ __align__(16) char VT[32768];
  __shared__ __align__(16) char P[8192];
  __shared__ int   stt[64];
  __shared__ float scl[64];

  const int blk = blockIdx.x;
  const int cpg = g * 64;
  const int b = blk / cpg, rem = blk % cpg;
  const int hl = rem >> 6, c = rem & 63;
  const int tid = threadIdx.x, w = tid >> 6, l = tid & 63;
  const int m = l & 15, gq = l >> 4;

  if (tid < 64) {
    const int s = st[(size_t)((b * 8 + hbase + hl) * 4096) + c * 64 + tid];
    stt[tid] = s;
    scl[tid] = scale[b * 4096 + s];
  }
  __syncthreads();

  const size_t qkbase = (size_t)b * 4096;
  f32x4 accS[4] = {};

  for (int half = 0; half < 2; ++half) {
    #pragma unroll
    for (int it = 0; it < 8; ++it) {
      const int blk16 = it * 256 + tid;
      const int row = blk16 >> 5, u = blk16 & 31;
      const uint4 dat = *(const uint4*)(qk_b + (qkbase + stt[row]) * 512 + half * 256 + u * 8);
      *(uint4*)(Q + ((row * 512 + u * 16) ^ ((row & 7) << 4))) = dat;
    }
    __syncthreads();
    #pragma unroll
    for (int kf = 0; kf < 8; ++kf) {
      const int arow = w * 16 + m;
      const short8 af = *(const short8*)(Q + ((arow * 512 + kf * 64 + gq * 16) ^ ((arow & 7) << 4)));
      #pragma unroll
      for (int jt = 0; jt < 4; ++jt) {
        const int brow = jt * 16 + m;
        const short8 bf = *(const short8*)(Q + ((brow * 512 + kf * 64 + gq * 16) ^ ((brow & 7) << 4)));
        accS[jt] = __builtin_amdgcn_mfma_f32_16x16x32_bf16(af, bf, accS[jt], 0, 0, 0);
      }
    }
    __syncthreads();
  }

  #pragma unroll
  for (int jt = 0; jt < 4; ++jt)
    #pragma unroll
    for (int r = 0; r < 4; ++r) {
      const int i = w * 16 + gq * 4 + r;
      const int j = jt * 16 + m;
      *(ushort_t*)(P + ((i * 128 + j * 2) ^ ((i & 7) << 4))) = f2b(accS[jt][r] * scl[j]);
    }

  const size_t sobase = (size_t)(b * g + hl) * 4096;
  for (int half = 0; half < 2; ++half) {
    #pragma unroll
    for (int it = 0; it < 8; ++it) {
      const int blk16 = it * 256 + tid;
      const int j = blk16 >> 5, u = blk16 & 31;
      const uint4 dat = *(const uint4*)(v_b + (qkbase + stt[j]) * 512 + half * 256 + u * 8);
      const ushort_t* e = (const ushort_t*)&dat;
      #pragma unroll
      for (int ee = 0; ee < 8; ++ee) {
        const int d = u * 8 + ee;
        *(ushort_t*)(VT + ((d * 128 + j * 2) ^ (((d ^ (d >> 3)) & 7) << 4))) = e[ee];
      }
    }
    __syncthreads();

    short8 ap[2];
    #pragma unroll
    for (int kf = 0; kf < 2; ++kf) {
      const int i = w * 16 + m;
      ap[kf] = *(const short8*)(P + ((i * 128 + kf * 64 + gq * 16) ^ ((i & 7) << 4)));
    }
    f32x4 accO[16] = {};
    #pragma unroll
    for (int dt = 0; dt < 16; ++dt) {
      #pragma unroll
      for (int kf = 0; kf < 2; ++kf) {
        const int d = dt * 16 + m;
        const short8 bv = *(const short8*)(VT + ((d * 128 + kf * 64 + gq * 16) ^ (((d ^ (d >> 3)) & 7) << 4)));
        accO[dt] = __builtin_amdgcn_mfma_f32_16x16x32_bf16(ap[kf], bv, accO[dt], 0, 0, 0);
      }
    }
    __syncthreads();

    #pragma unroll
    for (int dt = 0; dt < 16; ++dt)
      #pragma unroll
      for (int r = 0; r < 4; ++r) {
        const int i = w * 16 + gq * 4 + r;
        const int dcol = dt * 16 + m;
        *(ushort_t*)(Q + ((i * 512 + dcol * 2) ^ ((i & 7) << 4))) = f2b(accO[dt][r]);
      }
    __syncthreads();

    #pragma unroll
    for (int it = 0; it < 8; ++it) {
      const int blk16 = it * 256 + tid;
      const int row = blk16 >> 5, u = blk16 & 31;
      const uint4 dat = *(const uint4*)(Q + ((row * 512 + u * 16) ^ ((row & 7) << 4)));
      *(uint4*)(so + (sobase + stt[row]) * 512 + half * 256 + u * 8) = dat;
    }
  }
}

// -------- gather: o_b[tok][:] (+)= sum_{hl<g} so[(b*g+hl)*4096 + t][:], bf16 --------
__global__ __launch_bounds__(256) void gather_kernel(
    const ushort_t* __restrict__ so, ushort_t* __restrict__ o_b, int g, int first)
{
  const int tok = blockIdx.x;
  const int b = tok >> 12, t = tok & 4095;
  const int d0 = threadIdx.x * 2;
  ushort_t* dst = o_b + (size_t)tok * 512 + d0;
  float ax = 0.f, ay = 0.f;
  if (!first) {
    const unsigned u = *(const unsigned*)dst;
    ax = b2f(u & 0xffffu); ay = b2f(u >> 16);
  }
  const size_t stride = (size_t)4096 * 512;
  const ushort_t* src = so + ((size_t)(b * g) * 4096 + t) * 512 + d0;
  for (int hlp = 0; hlp < g; ++hlp) {
    const unsigned u = *(const unsigned*)src;
    ax += b2f(u & 0xffffu);
    ay += b2f(u >> 16);
    src += stride;
  }
  *(unsigned*)dst = ((unsigned)f2b(ay) << 16) | (unsigned)f2b(ax);
}

extern "C" void kernel_launch(void* const* d_in, const int* in_sizes, int n_in,
                              void* d_out, int out_size, void* d_ws, size_t ws_size,
                              hipStream_t stream) {
  const float* x         = (const float*)d_in[0];
  const float* rotations = (const float*)d_in[1];
  const float* w_qk      = (const float*)d_in[2];
  const float* b_qk      = (const float*)d_in[3];
  const float* w_v       = (const float*)d_in[4];
  const float* b_v       = (const float*)d_in[5];
  const float* w_out     = (const float*)d_in[6];
  const float* b_out     = (const float*)d_in[7];
  float* out = (float*)d_out;
  char* ws = (char*)d_ws;

  ushort_t* xh      = (ushort_t*)(ws);                  // 16.78 MB
  ushort_t* xl      = (ushort_t*)(ws + 16777216);       // 16.78 MB
  ushort_t* qk_hi   = (ushort_t*)(ws + 33554432);       // 16.78 MB
  ushort_t* v_b     = (ushort_t*)(ws + 50331648);       // 16.78 MB
  float*    rot     = (float*)(ws + 67108864);          // 16.78 MB (dead after fallback)
  ushort_t* o_b     = (ushort_t*)(ws + 67108864);       // alias: lives after gather
  ushort_t* wqkTh   = (ushort_t*)(ws + 83886080);       // 512 KB
  ushort_t* wvT     = (ushort_t*)(ws + 84410368);       // 512 KB
  ushort_t* woT     = (ushort_t*)(ws + 84934656);       // 512 KB
  ushort_t* W2Th    = (ushort_t*)(ws + 85458944);       // 256 KB
  ushort_t* W2Tl    = (ushort_t*)(ws + 85721088);       // 256 KB
  float*    b2      = (float*)(ws + 85983232);          // 1 KB (pad to 4K)
  float*    scale   = (float*)(ws + 85987328);          // 64 KB
  int*      buckets = (int*)(ws + 86052864);            // 512 KB
  int*      st      = (int*)(ws + 86577152);            // 512 KB
  int*      mlist   = (int*)(ws + 87101440);            // 512 KB (cap 131072: can't overflow)
  int*      mcount  = (int*)(ws + 87625728);            // 4 KB
  ushort_t* so      = (ushort_t*)(ws + 87629824);       // g * 16.78 MB
  const size_t so_off = 87629824;

  int g = 1;
  for (int cand = 8; cand >= 1; cand >>= 1)
    if (so_off + (size_t)cand * 16777216ull <= ws_size) { g = cand; break; }

  const dim3 blk256(256);
  hipLaunchKernelGGL(prep_kernel, dim3(5377), blk256, 0, stream,
                     x, w_qk, b_qk, rotations, w_v, w_out,
                     xh, xl, wqkTh, wvT, woT, W2Th, W2Tl, b2, mcount);

  hipLaunchKernelGGL(gemm_mfma_x2, dim3(128, 4), blk256, 0, stream, xh, xl, wqkTh, b_qk, qk_hi);
  hipLaunchKernelGGL(gemm_mfma, dim3(128, 4), blk256, 0, stream, xh, wvT, b_v, (float*)0, v_b, 1);
  hipLaunchKernelGGL(rot3_mfma, dim3(128, 2), blk256, 0, stream, xh, xl, W2Th, W2Tl, b2, rot);

  hipLaunchKernelGGL(argmax_scale, dim3(20480), blk256, 0, stream,
                     rot, buckets, mlist, mcount, 1.5e-3f, qk_hi, scale);
  hipLaunchKernelGGL(bucket_fallback, dim3(1024), dim3(512), 0, stream,
                     x, w_qk, b_qk, rotations, mlist, mcount, buckets);
  hipLaunchKernelGGL(sort_kernel, dim3(32), blk256, 0, stream, buckets, st);

  const int passes = 8 / g;
  for (int p = 0; p < passes; ++p) {
    const int hbase = p * g;
    hipLaunchKernelGGL(attn_mfma, dim3(4 * g * 64), blk256, 0, stream,
                       qk_hi, v_b, scale, st, so, g, hbase);
    hipLaunchKernelGGL(gather_kernel, dim3(16384), blk256, 0, stream,
                       so, o_b, g, (p == 0) ? 1 : 0);
  }

  hipLaunchKernelGGL(gemm_mfma, dim3(128, 4), blk256, 0, stream, o_b, woT, b_out, out, (ushort_t*)0, 0);
}

// Round 11
// 319.899 us; speedup vs baseline: 1.3052x; 1.0166x over previous
//
#include <hip/hip_runtime.h>

// LSH attention, B=4, T=4096, D=512, H=8 hashes, 64 buckets/hash, bucket size 64.
// Round 11: T14 stage-ahead pipelining (race-free form: loads issued after a
// barrier, consumed after the NEXT barrier, so the implicit vmcnt(0) drain
// lands after the overlapped compute).
//  - attn: qk-h1 / V-h0 / V-h1 register-prefetch under S/PV compute phases;
//    flush(h0) overlapped with PV(h1). 13 -> 10 barriers.
//  - gemm_mfma (v + out): double-buffered LDS, STAGE(next) before compute(cur).

typedef __attribute__((ext_vector_type(8))) short short8;
typedef __attribute__((ext_vector_type(4))) float f32x4;
typedef unsigned short ushort_t;

__device__ __forceinline__ ushort_t f2b(float f) {
  union { float f; unsigned u; } x; x.f = f;
  unsigned r = x.u + 0x7fffu + ((x.u >> 16) & 1u);
  return (ushort_t)(r >> 16);
}
__device__ __forceinline__ float b2f(unsigned b) {
  union { unsigned u; float f; } x; x.u = b << 16;
  return x.f;
}
__device__ __forceinline__ void gload16(void* lds, const void* gp) {
  __builtin_amdgcn_global_load_lds(
      (const __attribute__((address_space(1))) unsigned int*)gp,
      (__attribute__((address_space(3))) unsigned int*)lds, 16, 0, 0);
}

// -------- fused prep: split_x | transpose_cvt x3 | w2_split | mcount=0 --------
__global__ __launch_bounds__(256) void prep_kernel(
    const float* __restrict__ x, const float* __restrict__ w_qk,
    const float* __restrict__ b_qk, const float* __restrict__ R,
    const float* __restrict__ w_v, const float* __restrict__ w_out,
    ushort_t* __restrict__ xh, ushort_t* __restrict__ xl,
    ushort_t* __restrict__ wqkT, ushort_t* __restrict__ wvT, ushort_t* __restrict__ woT,
    ushort_t* __restrict__ W2Th, ushort_t* __restrict__ W2Tl, float* __restrict__ b2,
    int* __restrict__ mcount)
{
  __shared__ float t[32][33];
  __shared__ float wrow[512];
  const int blk = blockIdx.x, tid = threadIdx.x;
  if (blk == 0 && tid == 0) mcount[0] = 0;

  if (blk < 4096) {                      // ---- split_x ----
    const int i = blk * 256 + tid;
    const float4 a = *(const float4*)(x + (size_t)i * 8);
    const float4 c = *(const float4*)(x + (size_t)i * 8 + 4);
    float v[8] = { a.x, a.y, a.z, a.w, c.x, c.y, c.z, c.w };
    ushort_t hi[8], lo[8];
    #pragma unroll
    for (int k = 0; k < 8; ++k) {
      hi[k] = f2b(v[k]);
      lo[k] = f2b(v[k] - b2f(hi[k]));
    }
    *(uint4*)(xh + (size_t)i * 8) = *(const uint4*)hi;
    *(uint4*)(xl + (size_t)i * 8) = *(const uint4*)lo;
  } else if (blk < 4864) {               // ---- transpose_cvt x3 ----
    const int idx = blk - 4096;
    const int mat = idx >> 8, r = idx & 255;
    const float* W  = (mat == 0) ? w_qk : (mat == 1) ? w_v : w_out;
    ushort_t*   Wt  = (mat == 0) ? wqkT : (mat == 1) ? wvT : woT;
    const int bx = (r & 15) * 32, by = (r >> 4) * 32;
    const int tx = tid & 31, ty = tid >> 5;
    #pragma unroll
    for (int j = 0; j < 4; ++j)
      t[ty + j*8][tx] = W[(size_t)(by + ty + j*8) * 512 + bx + tx];
    __syncthreads();
    #pragma unroll
    for (int j = 0; j < 4; ++j)
      Wt[(size_t)(bx + ty + j*8) * 512 + by + tx] = f2b(t[tx][ty + j*8]);
  } else {                               // ---- w2_split ----
    const int e = blk - 4864, j = tid;   // e in [0,513), j in [0,256)
    const float* src = (e < 512) ? (w_qk + (size_t)e * 512) : b_qk;
    wrow[j]       = src[j];
    wrow[j + 256] = src[j + 256];
    __syncthreads();
    float acc = 0.f;
    for (int f = 0; f < 512; ++f)
      acc = fmaf(wrow[f], R[(size_t)f * 256 + j], acc);
    if (e < 512) {
      const ushort_t hi = f2b(acc);
      W2Th[(size_t)j * 512 + e] = hi;
      W2Tl[(size_t)j * 512 + e] = f2b(acc - b2f(hi));
    } else {
      b2[j] = acc;
    }
  }
}

// ---- bf16 MFMA GEMM (1 product), double-buffered stage-ahead ----
__global__ __launch_bounds__(256, 2) void gemm_mfma(
    const ushort_t* __restrict__ A, const ushort_t* __restrict__ Wt,
    const float* __restrict__ bias, float* __restrict__ Cf,
    ushort_t* __restrict__ Cb, int out_bf16)
{
  __shared__ __align__(16) char Al[32768];   // 2 x 16KB
  __shared__ __align__(16) char Bl[32768];
  const int bm = blockIdx.x * 128, bn = blockIdx.y * 128;
  const int tid = threadIdx.x, w = tid >> 6, l = tid & 63;
  const int m = l & 15, gq = l >> 4;
  f32x4 acc[2][8] = {};

#define STAGE1(NB, K0) { \
    _Pragma("unroll") \
    for (int j = 0; j < 4; ++j) { \
      const int row = w * 32 + j * 8 + (l >> 3); \
      const int ch = (l & 7) ^ (row & 7); \
      const int dst = (NB) * 16384 + w * 4096 + j * 1024 + l * 16; \
      gload16(Al + dst, A  + (size_t)(bm + row) * 512 + (K0) + ch * 8); \
      gload16(Bl + dst, Wt + (size_t)(bn + row) * 512 + (K0) + ch * 8); \
    } }

  STAGE1(0, 0)
  __syncthreads();
  for (int t = 0; t < 8; ++t) {
    const int cur = t & 1;
    if (t < 7) STAGE1(cur ^ 1, (t + 1) * 64)
    #pragma unroll
    for (int ks = 0; ks < 2; ++ks) {
      short8 bfr[8];
      #pragma unroll
      for (int tj = 0; tj < 8; ++tj) {
        const int brow = tj * 16 + m;
        bfr[tj] = *(const short8*)(Bl + cur * 16384 + ((brow * 128 + ks * 64 + gq * 16) ^ ((brow & 7) << 4)));
      }
      #pragma unroll
      for (int ti = 0; ti < 2; ++ti) {
        const int arow = w * 32 + ti * 16 + m;
        const short8 af = *(const short8*)(Al + cur * 16384 + ((arow * 128 + ks * 64 + gq * 16) ^ ((arow & 7) << 4)));
        #pragma unroll
        for (int tj = 0; tj < 8; ++tj)
          acc[ti][tj] = __builtin_amdgcn_mfma_f32_16x16x32_bf16(af, bfr[tj], acc[ti][tj], 0, 0, 0);
      }
    }
    __syncthreads();
  }
#undef STAGE1
  #pragma unroll
  for (int ti = 0; ti < 2; ++ti)
    #pragma unroll
    for (int tj = 0; tj < 8; ++tj) {
      const int col = bn + tj * 16 + m;
      const float bvv = bias[col];
      #pragma unroll
      for (int r2 = 0; r2 < 4; ++r2) {
        const int row = bm + w * 32 + ti * 16 + gq * 4 + r2;
        const float oo = acc[ti][tj][r2] + bvv;
        if (out_bf16) Cb[(size_t)row * 512 + col] = f2b(oo);
        else          Cf[(size_t)row * 512 + col] = oo;
      }
    }
}

// ---- bf16 MFMA GEMM (2 A-products): C = (Ah+Al) @ Wt^T + bias -> bf16 ----
__global__ __launch_bounds__(256, 3) void gemm_mfma_x2(
    const ushort_t* __restrict__ Ah, const ushort_t* __restrict__ Al,
    const ushort_t* __restrict__ Wt, const float* __restrict__ bias,
    ushort_t* __restrict__ Cb)
{
  __shared__ __align__(16) char AH[16384], AL[16384], BH[16384];
  const int bm = blockIdx.x * 128, bn = blockIdx.y * 128;
  const int tid = threadIdx.x, w = tid >> 6, l = tid & 63;
  const int m = l & 15, gq = l >> 4;
  f32x4 acc[2][8] = {};
  for (int k0 = 0; k0 < 512; k0 += 64) {
    #pragma unroll
    for (int j = 0; j < 4; ++j) {
      const int row = w * 32 + j * 8 + (l >> 3);
      const int ch = (l & 7) ^ (row & 7);
      const int dst = w * 4096 + j * 1024 + l * 16;
      gload16(AH + dst, Ah + (size_t)(bm + row) * 512 + k0 + ch * 8);
      gload16(AL + dst, Al + (size_t)(bm + row) * 512 + k0 + ch * 8);
      gload16(BH + dst, Wt + (size_t)(bn + row) * 512 + k0 + ch * 8);
    }
    __syncthreads();
    #pragma unroll
    for (int ks = 0; ks < 2; ++ks) {
      short8 bfr[8];
      #pragma unroll
      for (int tj = 0; tj < 8; ++tj) {
        const int brow = tj * 16 + m;
        bfr[tj] = *(const short8*)(BH + ((brow * 128 + ks * 64 + gq * 16) ^ ((brow & 7) << 4)));
      }
      #pragma unroll
      for (int ti = 0; ti < 2; ++ti) {
        const int arow = w * 32 + ti * 16 + m;
        const int aa = (arow * 128 + ks * 64 + gq * 16) ^ ((arow & 7) << 4);
        const short8 ah8 = *(const short8*)(AH + aa);
        const short8 al8 = *(const short8*)(AL + aa);
        #pragma unroll
        for (int tj = 0; tj < 8; ++tj) {
          acc[ti][tj] = __builtin_amdgcn_mfma_f32_16x16x32_bf16(ah8, bfr[tj], acc[ti][tj], 0, 0, 0);
          acc[ti][tj] = __builtin_amdgcn_mfma_f32_16x16x32_bf16(al8, bfr[tj], acc[ti][tj], 0, 0, 0);
        }
      }
    }
    __syncthreads();
  }
  #pragma unroll
  for (int ti = 0; ti < 2; ++ti)
    #pragma unroll
    for (int tj = 0; tj < 8; ++tj) {
      const int col = bn + tj * 16 + m;
      const float bvv = bias[col];
      #pragma unroll
      for (int r2 = 0; r2 < 4; ++r2) {
        const int row = bm + w * 32 + ti * 16 + gq * 4 + r2;
        Cb[(size_t)row * 512 + col] = f2b(acc[ti][tj][r2] + bvv);
      }
    }
}

// ---- rot = (xh+xl)@(W2h+W2l)^T + b2 via 3 MFMA products (lo*lo dropped), fp32 ----
__global__ __launch_bounds__(256, 2) void rot3_mfma(
    const ushort_t* __restrict__ Ah, const ushort_t* __restrict__ Al,
    const ushort_t* __restrict__ Bh, const ushort_t* __restrict__ Bl,
    const float* __restrict__ b2, float* __restrict__ rot)
{
  __shared__ __align__(16) char AH[16384], AL[16384], BH[16384], BL[16384];
  const int bm = blockIdx.x * 128, bn = blockIdx.y * 128;
  const int tid = threadIdx.x, w = tid >> 6, l = tid & 63;
  const int m = l & 15, gq = l >> 4;
  f32x4 acc[2][8] = {};
  for (int k0 = 0; k0 < 512; k0 += 64) {
    #pragma unroll
    for (int j = 0; j < 4; ++j) {
      const int row = w * 32 + j * 8 + (l >> 3);
      const int ch = (l & 7) ^ (row & 7);
      const int dst = w * 4096 + j * 1024 + l * 16;
      gload16(AH + dst, Ah + (size_t)(bm + row) * 512 + k0 + ch * 8);
      gload16(AL + dst, Al + (size_t)(bm + row) * 512 + k0 + ch * 8);
      gload16(BH + dst, Bh + (size_t)(bn + row) * 512 + k0 + ch * 8);
      gload16(BL + dst, Bl + (size_t)(bn + row) * 512 + k0 + ch * 8);
    }
    __syncthreads();
    #pragma unroll
    for (int ks = 0; ks < 2; ++ks) {
      short8 bh8[8], bl8[8];
      #pragma unroll
      for (int tj = 0; tj < 8; ++tj) {
        const int ba = ((tj * 16 + m) * 128 + ks * 64 + gq * 16) ^ (((tj * 16 + m) & 7) << 4);
        bh8[tj] = *(const short8*)(BH + ba);
        bl8[tj] = *(const short8*)(BL + ba);
      }
      #pragma unroll
      for (int ti = 0; ti < 2; ++ti) {
        const int arow = w * 32 + ti * 16 + m;
        const int aa = (arow * 128 + ks * 64 + gq * 16) ^ ((arow & 7) << 4);
        const short8 ah8 = *(const short8*)(AH + aa);
        const short8 al8 = *(const short8*)(AL + aa);
        #pragma unroll
        for (int tj = 0; tj < 8; ++tj) {
          acc[ti][tj] = __builtin_amdgcn_mfma_f32_16x16x32_bf16(ah8, bh8[tj], acc[ti][tj], 0, 0, 0);
          acc[ti][tj] = __builtin_amdgcn_mfma_f32_16x16x32_bf16(al8, bh8[tj], acc[ti][tj], 0, 0, 0);
          acc[ti][tj] = __builtin_amdgcn_mfma_f32_16x16x32_bf16(ah8, bl8[tj], acc[ti][tj], 0, 0, 0);
        }
      }
    }
    __syncthreads();
  }
  #pragma unroll
  for (int ti = 0; ti < 2; ++ti)
    #pragma unroll
    for (int tj = 0; tj < 8; ++tj) {
      const int col = bn + tj * 16 + m;
      const float bvv = b2[col];
      #pragma unroll
      for (int r2 = 0; r2 < 4; ++r2) {
        const int row = bm + w * 32 + ti * 16 + gq * 4 + r2;
        rot[(size_t)row * 256 + col] = acc[ti][tj][r2] + bvv;
      }
    }
}

// ---- fused: argmax+margin (blocks < 16384) | scale (blocks >= 16384) ----
__global__ __launch_bounds__(256) void argmax_scale(
    const float* __restrict__ rot, int* __restrict__ buckets,
    int* __restrict__ mlist, int* __restrict__ mcount, float tau,
    const ushort_t* __restrict__ qh, float* __restrict__ scale)
{
  const int blk = blockIdx.x;
  if (blk < 16384) {
    const int tok = blk;
    const int j = threadIdx.x;             // j = h*32 + i
    const float r = rot[(size_t)tok * 256 + j];
    float m1, m2; int i1;
    if (r >= 0.f) { m1 = r;  i1 = j & 31;        m2 = -r; }
    else          { m1 = -r; i1 = (j & 31) + 32; m2 = r;  }
    #pragma unroll
    for (int off = 16; off; off >>= 1) {
      const float om1 = __shfl_xor(m1, off);
      const int   oi1 = __shfl_xor(i1, off);
      const float om2 = __shfl_xor(m2, off);
      float loser;
      if (om1 > m1 || (om1 == m1 && oi1 < i1)) { loser = m1; m1 = om1; i1 = oi1; }
      else loser = om1;
      m2 = fmaxf(fmaxf(m2, om2), loser);
    }
    if ((j & 31) == 0) {
      const int h = j >> 5, b = tok >> 12, t = tok & 4095;
      buckets[((b << 3) + h) * 4096 + t] = i1;
      if (m1 - m2 < tau) {
        const int k = atomicAdd(mcount, 1);
        mlist[k] = (((b << 3) + h) << 12) | t;
      }
    }
  } else {
    const int wave = threadIdx.x >> 6, lane = threadIdx.x & 63;
    const int tok = (blk - 16384) * 4 + wave;
    const uint4 H = *(const uint4*)(qh + (size_t)tok * 512 + lane * 8);
    const unsigned* hp = (const unsigned*)&H;
    float s = 0.f;
    #pragma unroll
    for (int e = 0; e < 4; ++e) {
      const float v0 = b2f(hp[e] & 0xffffu);
      const float v1 = b2f(hp[e] >> 16);
      s += v0 * v0 + v1 * v1;
    }
    #pragma unroll
    for (int off = 32; off; off >>= 1) s += __shfl_down(s, off);
    if (lane == 0) {
      const float nn = fmaxf(sqrtf(s), 1e-12f);
      scale[tok] = 0.044194173824159216f / nn;   // 512^-0.5 / norm
    }
  }
}

// ---- exact np-chain fallback for marginal (b,h,t) pairs ----
__global__ __launch_bounds__(512) void bucket_fallback(
    const float* __restrict__ x, const float* __restrict__ w_qk,
    const float* __restrict__ b_qk, const float* __restrict__ R,
    const int* __restrict__ mlist, const int* __restrict__ mcount,
    int* __restrict__ buckets)
{
  __shared__ float qkrow[512];
  const int n = mcount[0];
  for (int ii = blockIdx.x; ii < n; ii += gridDim.x) {
    const int mm = mlist[ii];
    const int bh = mm >> 12, t = mm & 4095;
    const int b = bh >> 3, h = bh & 7;
    const float* xr = x + ((size_t)b * 4096 + t) * 512;
    {
      const int c = threadIdx.x;
      float a0 = 0.f;
      for (int f = 0; f < 512; ++f) a0 = fmaf(xr[f], w_qk[(size_t)f * 512 + c], a0);
      qkrow[c] = a0 + b_qk[c];
    }
    __syncthreads();
    if (threadIdx.x < 32) {
      const int col = h * 32 + threadIdx.x;
      float a0 = 0.f;
      for (int f = 0; f < 512; ++f) a0 = fmaf(qkrow[f], R[(size_t)f * 256 + col], a0);
      float m1; int i1;
      if (a0 >= 0.f) { m1 = a0;  i1 = threadIdx.x; }
      else           { m1 = -a0; i1 = threadIdx.x + 32; }
      #pragma unroll
      for (int off = 16; off; off >>= 1) {
        const float om = __shfl_xor(m1, off);
        const int   oi = __shfl_xor(i1, off);
        if (om > m1 || (om == m1 && oi < i1)) { m1 = om; i1 = oi; }
      }
      if (threadIdx.x == 0) buckets[(size_t)bh * 4096 + t] = i1;
    }
    __syncthreads();
  }
}

// -------- stable counting sort per (b,h): tokens by (bucket, t) --------
__global__ __launch_bounds__(256) void sort_kernel(
    const int* __restrict__ buckets, int* __restrict__ st)
{
  __shared__ int bk_lds[4096];
  __shared__ int cnt[4][64];
  __shared__ int startq[4][64];
  const int tid = threadIdx.x;
  const int base = blockIdx.x * 4096;     // blockIdx = b*8+h
  for (int t = tid; t < 4096; t += 256) bk_lds[t] = buckets[base + t];
  __syncthreads();
  const int wave = tid >> 6, lane = tid & 63;
  const int q0 = wave * 1024;
  int c = 0;
  for (int t = 0; t < 1024; ++t) c += (bk_lds[q0 + t] == lane);
  cnt[wave][lane] = c;
  __syncthreads();
  if (tid < 64) {
    const int c0 = cnt[0][tid], c1 = cnt[1][tid], c2 = cnt[2][tid], c3 = cnt[3][tid];
    const int tot = c0 + c1 + c2 + c3;
    int ex = tot;
    #pragma unroll
    for (int off = 1; off < 64; off <<= 1) {
      const int nn = __shfl_up(ex, off);
      if (lane >= off) ex += nn;
    }
    const int bucket_start = ex - tot;
    startq[0][tid] = bucket_start;
    startq[1][tid] = bucket_start + c0;
    startq[2][tid] = bucket_start + c0 + c1;
    startq[3][tid] = bucket_start + c0 + c1 + c2;
  }
  __syncthreads();
  int cur = startq[wave][lane];
  for (int t = 0; t < 1024; ++t) {
    if (bk_lds[q0 + t] == lane) { st[base + cur] = q0 + t; cur++; }
  }
}

// -------- MFMA chunked attention: round-7 buffers + T14 stage-ahead --------
__global__ __launch_bounds__(256, 2) void attn_mfma(
    const ushort_t* __restrict__ qk_b, const ushort_t* __restrict__ v_b,
    const float* __restrict__ scale, const int* __restrict__ st,
    ushort_t* __restrict__ so, int g, int hbase)
{
  __shared__ __align__(16) char Q[32768];
  __shared__ __align__(16) char VT[32768];
  __shared__ __align__(16) char P[8192];
  __shared__ int   stt[64];
  __shared__ float scl[64];

  const int blk = blockIdx.x;
  const int cpg = g * 64;
  const int b = blk / cpg, rem = blk % cpg;
  const int hl = rem >> 6, c = rem & 63;
  const int tid = threadIdx.x, w = tid >> 6, l = tid & 63;
  const int m = l & 15, gq = l >> 4;
  const int srow = tid >> 5, su = tid & 31;   // staging row/chunk for this thread (it-step stride 8 rows)

  if (tid < 64) {
    const int s = st[(size_t)((b * 8 + hbase + hl) * 4096) + c * 64 + tid];
    stt[tid] = s;
    scl[tid] = scale[b * 4096 + s];
  }
  __syncthreads();

  const size_t qkbase = (size_t)b * 4096;
  uint4 rg[8];

#define LOADG(SRC, HALF) { \
    _Pragma("unroll") \
    for (int it = 0; it < 8; ++it) { \
      const int row = it * 8 + srow; \
      rg[it] = *(const uint4*)((SRC) + (qkbase + stt[row]) * 512 + (HALF) * 256 + su * 8); \
    } }
#define WRITEQ() { \
    _Pragma("unroll") \
    for (int it = 0; it < 8; ++it) { \
      const int row = it * 8 + srow; \
      *(uint4*)(Q + ((row * 512 + su * 16) ^ ((row & 7) << 4))) = rg[it]; \
    } }
#define WRITEVT() { \
    _Pragma("unroll") \
    for (int it = 0; it < 8; ++it) { \
      const int j = it * 8 + srow; \
      const ushort_t* e = (const ushort_t*)&rg[it]; \
      _Pragma("unroll") \
      for (int ee = 0; ee < 8; ++ee) { \
        const int d = su * 8 + ee; \
        *(ushort_t*)(VT + ((d * 128 + j * 2) ^ (((d ^ (d >> 3)) & 7) << 4))) = e[ee]; \
      } \
    } }
#define COMPUTE_S() { \
    _Pragma("unroll") \
    for (int kf = 0; kf < 8; ++kf) { \
      const int arow = w * 16 + m; \
      const short8 af = *(const short8*)(Q + ((arow * 512 + kf * 64 + gq * 16) ^ ((arow & 7) << 4))); \
      _Pragma("unroll") \
      for (int jt = 0; jt < 4; ++jt) { \
        const int brow = jt * 16 + m; \
        const short8 bf = *(const short8*)(Q + ((brow * 512 + kf * 64 + gq * 16) ^ ((brow & 7) << 4))); \
        accS[jt] = __builtin_amdgcn_mfma_f32_16x16x32_bf16(af, bf, accS[jt], 0, 0, 0); \
      } \
    } }
#define COMPUTE_PV(ACCO) { \
    _Pragma("unroll") \
    for (int dt = 0; dt < 16; ++dt) { \
      _Pragma("unroll") \
      for (int kf = 0; kf < 2; ++kf) { \
        const int d = dt * 16 + m; \
        const short8 bv = *(const short8*)(VT + ((d * 128 + kf * 64 + gq * 16) ^ (((d ^ (d >> 3)) & 7) << 4))); \
        ACCO[dt] = __builtin_amdgcn_mfma_f32_16x16x32_bf16(ap[kf], bv, ACCO[dt], 0, 0, 0); \
      } \
    } }
#define BOUNCE(ACCO) { \
    _Pragma("unroll") \
    for (int dt = 0; dt < 16; ++dt) \
      _Pragma("unroll") \
      for (int r = 0; r < 4; ++r) { \
        const int i = w * 16 + gq * 4 + r; \
        const int dcol = dt * 16 + m; \
        *(ushort_t*)(Q + ((i * 512 + dcol * 2) ^ ((i & 7) << 4))) = f2b(ACCO[dt][r]); \
      } }
#define FLUSH(HALF) { \
    _Pragma("unroll") \
    for (int it = 0; it < 8; ++it) { \
      const int row = it * 8 + srow; \
      const uint4 dat = *(const uint4*)(Q + ((row * 512 + su * 16) ^ ((row & 7) << 4))); \
      *(uint4*)(so + (sobase + stt[row]) * 512 + (HALF) * 256 + su * 8) = dat; \
    } }

  f32x4 accS[4] = {};

  // ---- S phase ----
  LOADG(qk_b, 0)
  WRITEQ()
  __syncthreads();                 // Q(h0) ready
  LOADG(qk_b, 1)                   // in flight under S(h0)
  COMPUTE_S()
  __syncthreads();                 // rg arrived; Q(h0) readers done
  WRITEQ()
  __syncthreads();                 // Q(h1) ready
  LOADG(v_b, 0)                    // in flight under S(h1)
  COMPUTE_S()
  __syncthreads();                 // rg arrived; S done, Q free

  // ---- P + VT(h0) ----
  #pragma unroll
  for (int jt = 0; jt < 4; ++jt)
    #pragma unroll
    for (int r = 0; r < 4; ++r) {
      const int i = w * 16 + gq * 4 + r;
      const int j = jt * 16 + m;
      *(ushort_t*)(P + ((i * 128 + j * 2) ^ ((i & 7) << 4))) = f2b(accS[jt][r] * scl[j]);
    }
  WRITEVT()
  __syncthreads();                 // P + VT(h0) ready

  const size_t sobase = (size_t)(b * g + hl) * 4096;
  LOADG(v_b, 1)                    // in flight under PV(h0)
  short8 ap[2];
  #pragma unroll
  for (int kf = 0; kf < 2; ++kf) {
    const int i = w * 16 + m;
    ap[kf] = *(const short8*)(P + ((i * 128 + kf * 64 + gq * 16) ^ ((i & 7) << 4)));
  }
  f32x4 accO[16] = {};
  COMPUTE_PV(accO)
  __syncthreads();                 // rg arrived; VT(h0) readers done

  WRITEVT()                        // VT(h1)
  BOUNCE(accO)                     // O(h0) -> Q
  __syncthreads();                 // VT(h1) + bounce ready

  FLUSH(0)                         // overlaps with PV(h1)
  f32x4 accO2[16] = {};
  COMPUTE_PV(accO2)
  __syncthreads();                 // bounce readers done

  BOUNCE(accO2)
  __syncthreads();
  FLUSH(1)

#undef LOADG
#undef WRITEQ
#undef WRITEVT
#undef COMPUTE_S
#undef COMPUTE_PV
#undef BOUNCE
#undef FLUSH
}

// -------- gather: o_b[tok][:] (+)= sum_{hl<g} so[(b*g+hl)*4096 + t][:], bf16 --------
__global__ __launch_bounds__(256) void gather_kernel(
    const ushort_t* __restrict__ so, ushort_t* __restrict__ o_b, int g, int first)
{
  const int tok = blockIdx.x;
  const int b = tok >> 12, t = tok & 4095;
  const int d0 = threadIdx.x * 2;
  ushort_t* dst = o_b + (size_t)tok * 512 + d0;
  float ax = 0.f, ay = 0.f;
  if (!first) {
    const unsigned u = *(const unsigned*)dst;
    ax = b2f(u & 0xffffu); ay = b2f(u >> 16);
  }
  const size_t stride = (size_t)4096 * 512;
  const ushort_t* src = so + ((size_t)(b * g) * 4096 + t) * 512 + d0;
  for (int hlp = 0; hlp < g; ++hlp) {
    const unsigned u = *(const unsigned*)src;
    ax += b2f(u & 0xffffu);
    ay += b2f(u >> 16);
    src += stride;
  }
  *(unsigned*)dst = ((unsigned)f2b(ay) << 16) | (unsigned)f2b(ax);
}

extern "C" void kernel_launch(void* const* d_in, const int* in_sizes, int n_in,
                              void* d_out, int out_size, void* d_ws, size_t ws_size,
                              hipStream_t stream) {
  const float* x         = (const float*)d_in[0];
  const float* rotations = (const float*)d_in[1];
  const float* w_qk      = (const float*)d_in[2];
  const float* b_qk      = (const float*)d_in[3];
  const float* w_v       = (const float*)d_in[4];
  const float* b_v       = (const float*)d_in[5];
  const float* w_out     = (const float*)d_in[6];
  const float* b_out     = (const float*)d_in[7];
  float* out = (float*)d_out;
  char* ws = (char*)d_ws;

  ushort_t* xh      = (ushort_t*)(ws);                  // 16.78 MB
  ushort_t* xl      = (ushort_t*)(ws + 16777216);       // 16.78 MB
  ushort_t* qk_hi   = (ushort_t*)(ws + 33554432);       // 16.78 MB
  ushort_t* v_b     = (ushort_t*)(ws + 50331648);       // 16.78 MB
  float*    rot     = (float*)(ws + 67108864);          // 16.78 MB (dead after fallback)
  ushort_t* o_b     = (ushort_t*)(ws + 67108864);       // alias: lives after gather
  ushort_t* wqkTh   = (ushort_t*)(ws + 83886080);       // 512 KB
  ushort_t* wvT     = (ushort_t*)(ws + 84410368);       // 512 KB
  ushort_t* woT     = (ushort_t*)(ws + 84934656);       // 512 KB
  ushort_t* W2Th    = (ushort_t*)(ws + 85458944);       // 256 KB
  ushort_t* W2Tl    = (ushort_t*)(ws + 85721088);       // 256 KB
  float*    b2      = (float*)(ws + 85983232);          // 1 KB (pad to 4K)
  float*    scale   = (float*)(ws + 85987328);          // 64 KB
  int*      buckets = (int*)(ws + 86052864);            // 512 KB
  int*      st      = (int*)(ws + 86577152);            // 512 KB
  int*      mlist   = (int*)(ws + 87101440);            // 512 KB (cap 131072: can't overflow)
  int*      mcount  = (int*)(ws + 87625728);            // 4 KB
  ushort_t* so      = (ushort_t*)(ws + 87629824);       // g * 16.78 MB
  const size_t so_off = 87629824;

  int g = 1;
  for (int cand = 8; cand >= 1; cand >>= 1)
    if (so_off + (size_t)cand * 16777216ull <= ws_size) { g = cand; break; }

  const dim3 blk256(256);
  hipLaunchKernelGGL(prep_kernel, dim3(5377), blk256, 0, stream,
                     x, w_qk, b_qk, rotations, w_v, w_out,
                     xh, xl, wqkTh, wvT, woT, W2Th, W2Tl, b2, mcount);

  hipLaunchKernelGGL(gemm_mfma_x2, dim3(128, 4), blk256, 0, stream, xh, xl, wqkTh, b_qk, qk_hi);
  hipLaunchKernelGGL(gemm_mfma, dim3(128, 4), blk256, 0, stream, xh, wvT, b_v, (float*)0, v_b, 1);
  hipLaunchKernelGGL(rot3_mfma, dim3(128, 2), blk256, 0, stream, xh, xl, W2Th, W2Tl, b2, rot);

  hipLaunchKernelGGL(argmax_scale, dim3(20480), blk256, 0, stream,
                     rot, buckets, mlist, mcount, 1.5e-3f, qk_hi, scale);
  hipLaunchKernelGGL(bucket_fallback, dim3(1024), dim3(512), 0, stream,
                     x, w_qk, b_qk, rotations, mlist, mcount, buckets);
  hipLaunchKernelGGL(sort_kernel, dim3(32), blk256, 0, stream, buckets, st);

  const int passes = 8 / g;
  for (int p = 0; p < passes; ++p) {
    const int hbase = p * g;
    hipLaunchKernelGGL(attn_mfma, dim3(4 * g * 64), blk256, 0, stream,
                       qk_hi, v_b, scale, st, so, g, hbase);
    hipLaunchKernelGGL(gather_kernel, dim3(16384), blk256, 0, stream,
                       so, o_b, g, (p == 0) ? 1 : 0);
  }

  hipLaunchKernelGGL(gemm_mfma, dim3(128, 4), blk256, 0, stream, o_b, woT, b_out, out, (ushort_t*)0, 0);
}

// Round 12
// 256.545 us; speedup vs baseline: 1.6275x; 1.2470x over previous
//
#include <hip/hip_runtime.h>

// LSH attention, B=4, T=4096, D=512, H=8 hashes, 64 buckets/hash, bucket size 64.
// Round 12: sort_kernel rewritten as wave-parallel stable counting sort via
// 6-ballot bucket-match (serial depth 2048 -> ~80). Everything else unchanged
// from round 11 (attn T14 stage-ahead, dbuf gemm_mfma, fused prep/argmax).

typedef __attribute__((ext_vector_type(8))) short short8;
typedef __attribute__((ext_vector_type(4))) float f32x4;
typedef unsigned short ushort_t;

__device__ __forceinline__ ushort_t f2b(float f) {
  union { float f; unsigned u; } x; x.f = f;
  unsigned r = x.u + 0x7fffu + ((x.u >> 16) & 1u);
  return (ushort_t)(r >> 16);
}
__device__ __forceinline__ float b2f(unsigned b) {
  union { unsigned u; float f; } x; x.u = b << 16;
  return x.f;
}
__device__ __forceinline__ void gload16(void* lds, const void* gp) {
  __builtin_amdgcn_global_load_lds(
      (const __attribute__((address_space(1))) unsigned int*)gp,
      (__attribute__((address_space(3))) unsigned int*)lds, 16, 0, 0);
}

// -------- fused prep: split_x | transpose_cvt x3 | w2_split | mcount=0 --------
__global__ __launch_bounds__(256) void prep_kernel(
    const float* __restrict__ x, const float* __restrict__ w_qk,
    const float* __restrict__ b_qk, const float* __restrict__ R,
    const float* __restrict__ w_v, const float* __restrict__ w_out,
    ushort_t* __restrict__ xh, ushort_t* __restrict__ xl,
    ushort_t* __restrict__ wqkT, ushort_t* __restrict__ wvT, ushort_t* __restrict__ woT,
    ushort_t* __restrict__ W2Th, ushort_t* __restrict__ W2Tl, float* __restrict__ b2,
    int* __restrict__ mcount)
{
  __shared__ float t[32][33];
  __shared__ float wrow[512];
  const int blk = blockIdx.x, tid = threadIdx.x;
  if (blk == 0 && tid == 0) mcount[0] = 0;

  if (blk < 4096) {                      // ---- split_x ----
    const int i = blk * 256 + tid;
    const float4 a = *(const float4*)(x + (size_t)i * 8);
    const float4 c = *(const float4*)(x + (size_t)i * 8 + 4);
    float v[8] = { a.x, a.y, a.z, a.w, c.x, c.y, c.z, c.w };
    ushort_t hi[8], lo[8];
    #pragma unroll
    for (int k = 0; k < 8; ++k) {
      hi[k] = f2b(v[k]);
      lo[k] = f2b(v[k] - b2f(hi[k]));
    }
    *(uint4*)(xh + (size_t)i * 8) = *(const uint4*)hi;
    *(uint4*)(xl + (size_t)i * 8) = *(const uint4*)lo;
  } else if (blk < 4864) {               // ---- transpose_cvt x3 ----
    const int idx = blk - 4096;
    const int mat = idx >> 8, r = idx & 255;
    const float* W  = (mat == 0) ? w_qk : (mat == 1) ? w_v : w_out;
    ushort_t*   Wt  = (mat == 0) ? wqkT : (mat == 1) ? wvT : woT;
    const int bx = (r & 15) * 32, by = (r >> 4) * 32;
    const int tx = tid & 31, ty = tid >> 5;
    #pragma unroll
    for (int j = 0; j < 4; ++j)
      t[ty + j*8][tx] = W[(size_t)(by + ty + j*8) * 512 + bx + tx];
    __syncthreads();
    #pragma unroll
    for (int j = 0; j < 4; ++j)
      Wt[(size_t)(bx + ty + j*8) * 512 + by + tx] = f2b(t[tx][ty + j*8]);
  } else {                               // ---- w2_split ----
    const int e = blk - 4864, j = tid;   // e in [0,513), j in [0,256)
    const float* src = (e < 512) ? (w_qk + (size_t)e * 512) : b_qk;
    wrow[j]       = src[j];
    wrow[j + 256] = src[j + 256];
    __syncthreads();
    float acc = 0.f;
    for (int f = 0; f < 512; ++f)
      acc = fmaf(wrow[f], R[(size_t)f * 256 + j], acc);
    if (e < 512) {
      const ushort_t hi = f2b(acc);
      W2Th[(size_t)j * 512 + e] = hi;
      W2Tl[(size_t)j * 512 + e] = f2b(acc - b2f(hi));
    } else {
      b2[j] = acc;
    }
  }
}

// ---- bf16 MFMA GEMM (1 product), double-buffered stage-ahead ----
__global__ __launch_bounds__(256, 2) void gemm_mfma(
    const ushort_t* __restrict__ A, const ushort_t* __restrict__ Wt,
    const float* __restrict__ bias, float* __restrict__ Cf,
    ushort_t* __restrict__ Cb, int out_bf16)
{
  __shared__ __align__(16) char Al[32768];   // 2 x 16KB
  __shared__ __align__(16) char Bl[32768];
  const int bm = blockIdx.x * 128, bn = blockIdx.y * 128;
  const int tid = threadIdx.x, w = tid >> 6, l = tid & 63;
  const int m = l & 15, gq = l >> 4;
  f32x4 acc[2][8] = {};

#define STAGE1(NB, K0) { \
    _Pragma("unroll") \
    for (int j = 0; j < 4; ++j) { \
      const int row = w * 32 + j * 8 + (l >> 3); \
      const int ch = (l & 7) ^ (row & 7); \
      const int dst = (NB) * 16384 + w * 4096 + j * 1024 + l * 16; \
      gload16(Al + dst, A  + (size_t)(bm + row) * 512 + (K0) + ch * 8); \
      gload16(Bl + dst, Wt + (size_t)(bn + row) * 512 + (K0) + ch * 8); \
    } }

  STAGE1(0, 0)
  __syncthreads();
  for (int t = 0; t < 8; ++t) {
    const int cur = t & 1;
    if (t < 7) STAGE1(cur ^ 1, (t + 1) * 64)
    #pragma unroll
    for (int ks = 0; ks < 2; ++ks) {
      short8 bfr[8];
      #pragma unroll
      for (int tj = 0; tj < 8; ++tj) {
        const int brow = tj * 16 + m;
        bfr[tj] = *(const short8*)(Bl + cur * 16384 + ((brow * 128 + ks * 64 + gq * 16) ^ ((brow & 7) << 4)));
      }
      #pragma unroll
      for (int ti = 0; ti < 2; ++ti) {
        const int arow = w * 32 + ti * 16 + m;
        const short8 af = *(const short8*)(Al + cur * 16384 + ((arow * 128 + ks * 64 + gq * 16) ^ ((arow & 7) << 4)));
        #pragma unroll
        for (int tj = 0; tj < 8; ++tj)
          acc[ti][tj] = __builtin_amdgcn_mfma_f32_16x16x32_bf16(af, bfr[tj], acc[ti][tj], 0, 0, 0);
      }
    }
    __syncthreads();
  }
#undef STAGE1
  #pragma unroll
  for (int ti = 0; ti < 2; ++ti)
    #pragma unroll
    for (int tj = 0; tj < 8; ++tj) {
      const int col = bn + tj * 16 + m;
      const float bvv = bias[col];
      #pragma unroll
      for (int r2 = 0; r2 < 4; ++r2) {
        const int row = bm + w * 32 + ti * 16 + gq * 4 + r2;
        const float oo = acc[ti][tj][r2] + bvv;
        if (out_bf16) Cb[(size_t)row * 512 + col] = f2b(oo);
        else          Cf[(size_t)row * 512 + col] = oo;
      }
    }
}

// ---- bf16 MFMA GEMM (2 A-products): C = (Ah+Al) @ Wt^T + bias -> bf16 ----
__global__ __launch_bounds__(256, 3) void gemm_mfma_x2(
    const ushort_t* __restrict__ Ah, const ushort_t* __restrict__ Al,
    const ushort_t* __restrict__ Wt, const float* __restrict__ bias,
    ushort_t* __restrict__ Cb)
{
  __shared__ __align__(16) char AH[16384], AL[16384], BH[16384];
  const int bm = blockIdx.x * 128, bn = blockIdx.y * 128;
  const int tid = threadIdx.x, w = tid >> 6, l = tid & 63;
  const int m = l & 15, gq = l >> 4;
  f32x4 acc[2][8] = {};
  for (int k0 = 0; k0 < 512; k0 += 64) {
    #pragma unroll
    for (int j = 0; j < 4; ++j) {
      const int row = w * 32 + j * 8 + (l >> 3);
      const int ch = (l & 7) ^ (row & 7);
      const int dst = w * 4096 + j * 1024 + l * 16;
      gload16(AH + dst, Ah + (size_t)(bm + row) * 512 + k0 + ch * 8);
      gload16(AL + dst, Al + (size_t)(bm + row) * 512 + k0 + ch * 8);
      gload16(BH + dst, Wt + (size_t)(bn + row) * 512 + k0 + ch * 8);
    }
    __syncthreads();
    #pragma unroll
    for (int ks = 0; ks < 2; ++ks) {
      short8 bfr[8];
      #pragma unroll
      for (int tj = 0; tj < 8; ++tj) {
        const int brow = tj * 16 + m;
        bfr[tj] = *(const short8*)(BH + ((brow * 128 + ks * 64 + gq * 16) ^ ((brow & 7) << 4)));
      }
      #pragma unroll
      for (int ti = 0; ti < 2; ++ti) {
        const int arow = w * 32 + ti * 16 + m;
        const int aa = (arow * 128 + ks * 64 + gq * 16) ^ ((arow & 7) << 4);
        const short8 ah8 = *(const short8*)(AH + aa);
        const short8 al8 = *(const short8*)(AL + aa);
        #pragma unroll
        for (int tj = 0; tj < 8; ++tj) {
          acc[ti][tj] = __builtin_amdgcn_mfma_f32_16x16x32_bf16(ah8, bfr[tj], acc[ti][tj], 0, 0, 0);
          acc[ti][tj] = __builtin_amdgcn_mfma_f32_16x16x32_bf16(al8, bfr[tj], acc[ti][tj], 0, 0, 0);
        }
      }
    }
    __syncthreads();
  }
  #pragma unroll
  for (int ti = 0; ti < 2; ++ti)
    #pragma unroll
    for (int tj = 0; tj < 8; ++tj) {
      const int col = bn + tj * 16 + m;
      const float bvv = bias[col];
      #pragma unroll
      for (int r2 = 0; r2 < 4; ++r2) {
        const int row = bm + w * 32 + ti * 16 + gq * 4 + r2;
        Cb[(size_t)row * 512 + col] = f2b(acc[ti][tj][r2] + bvv);
      }
    }
}

// ---- rot = (xh+xl)@(W2h+W2l)^T + b2 via 3 MFMA products (lo*lo dropped), fp32 ----
__global__ __launch_bounds__(256, 2) void rot3_mfma(
    const ushort_t* __restrict__ Ah, const ushort_t* __restrict__ Al,
    const ushort_t* __restrict__ Bh, const ushort_t* __restrict__ Bl,
    const float* __restrict__ b2, float* __restrict__ rot)
{
  __shared__ __align__(16) char AH[16384], AL[16384], BH[16384], BL[16384];
  const int bm = blockIdx.x * 128, bn = blockIdx.y * 128;
  const int tid = threadIdx.x, w = tid >> 6, l = tid & 63;
  const int m = l & 15, gq = l >> 4;
  f32x4 acc[2][8] = {};
  for (int k0 = 0; k0 < 512; k0 += 64) {
    #pragma unroll
    for (int j = 0; j < 4; ++j) {
      const int row = w * 32 + j * 8 + (l >> 3);
      const int ch = (l & 7) ^ (row & 7);
      const int dst = w * 4096 + j * 1024 + l * 16;
      gload16(AH + dst, Ah + (size_t)(bm + row) * 512 + k0 + ch * 8);
      gload16(AL + dst, Al + (size_t)(bm + row) * 512 + k0 + ch * 8);
      gload16(BH + dst, Bh + (size_t)(bn + row) * 512 + k0 + ch * 8);
      gload16(BL + dst, Bl + (size_t)(bn + row) * 512 + k0 + ch * 8);
    }
    __syncthreads();
    #pragma unroll
    for (int ks = 0; ks < 2; ++ks) {
      short8 bh8[8], bl8[8];
      #pragma unroll
      for (int tj = 0; tj < 8; ++tj) {
        const int ba = ((tj * 16 + m) * 128 + ks * 64 + gq * 16) ^ (((tj * 16 + m) & 7) << 4);
        bh8[tj] = *(const short8*)(BH + ba);
        bl8[tj] = *(const short8*)(BL + ba);
      }
      #pragma unroll
      for (int ti = 0; ti < 2; ++ti) {
        const int arow = w * 32 + ti * 16 + m;
        const int aa = (arow * 128 + ks * 64 + gq * 16) ^ ((arow & 7) << 4);
        const short8 ah8 = *(const short8*)(AH + aa);
        const short8 al8 = *(const short8*)(AL + aa);
        #pragma unroll
        for (int tj = 0; tj < 8; ++tj) {
          acc[ti][tj] = __builtin_amdgcn_mfma_f32_16x16x32_bf16(ah8, bh8[tj], acc[ti][tj], 0, 0, 0);
          acc[ti][tj] = __builtin_amdgcn_mfma_f32_16x16x32_bf16(al8, bh8[tj], acc[ti][tj], 0, 0, 0);
          acc[ti][tj] = __builtin_amdgcn_mfma_f32_16x16x32_bf16(ah8, bl8[tj], acc[ti][tj], 0, 0, 0);
        }
      }
    }
    __syncthreads();
  }
  #pragma unroll
  for (int ti = 0; ti < 2; ++ti)
    #pragma unroll
    for (int tj = 0; tj < 8; ++tj) {
      const int col = bn + tj * 16 + m;
      const float bvv = b2[col];
      #pragma unroll
      for (int r2 = 0; r2 < 4; ++r2) {
        const int row = bm + w * 32 + ti * 16 + gq * 4 + r2;
        rot[(size_t)row * 256 + col] = acc[ti][tj][r2] + bvv;
      }
    }
}

// ---- fused: argmax+margin (blocks < 16384) | scale (blocks >= 16384) ----
__global__ __launch_bounds__(256) void argmax_scale(
    const float* __restrict__ rot, int* __restrict__ buckets,
    int* __restrict__ mlist, int* __restrict__ mcount, float tau,
    const ushort_t* __restrict__ qh, float* __restrict__ scale)
{
  const int blk = blockIdx.x;
  if (blk < 16384) {
    const int tok = blk;
    const int j = threadIdx.x;             // j = h*32 + i
    const float r = rot[(size_t)tok * 256 + j];
    float m1, m2; int i1;
    if (r >= 0.f) { m1 = r;  i1 = j & 31;        m2 = -r; }
    else          { m1 = -r; i1 = (j & 31) + 32; m2 = r;  }
    #pragma unroll
    for (int off = 16; off; off >>= 1) {
      const float om1 = __shfl_xor(m1, off);
      const int   oi1 = __shfl_xor(i1, off);
      const float om2 = __shfl_xor(m2, off);
      float loser;
      if (om1 > m1 || (om1 == m1 && oi1 < i1)) { loser = m1; m1 = om1; i1 = oi1; }
      else loser = om1;
      m2 = fmaxf(fmaxf(m2, om2), loser);
    }
    if ((j & 31) == 0) {
      const int h = j >> 5, b = tok >> 12, t = tok & 4095;
      buckets[((b << 3) + h) * 4096 + t] = i1;
      if (m1 - m2 < tau) {
        const int k = atomicAdd(mcount, 1);
        mlist[k] = (((b << 3) + h) << 12) | t;
      }
    }
  } else {
    const int wave = threadIdx.x >> 6, lane = threadIdx.x & 63;
    const int tok = (blk - 16384) * 4 + wave;
    const uint4 H = *(const uint4*)(qh + (size_t)tok * 512 + lane * 8);
    const unsigned* hp = (const unsigned*)&H;
    float s = 0.f;
    #pragma unroll
    for (int e = 0; e < 4; ++e) {
      const float v0 = b2f(hp[e] & 0xffffu);
      const float v1 = b2f(hp[e] >> 16);
      s += v0 * v0 + v1 * v1;
    }
    #pragma unroll
    for (int off = 32; off; off >>= 1) s += __shfl_down(s, off);
    if (lane == 0) {
      const float nn = fmaxf(sqrtf(s), 1e-12f);
      scale[tok] = 0.044194173824159216f / nn;   // 512^-0.5 / norm
    }
  }
}

// ---- exact np-chain fallback for marginal (b,h,t) pairs ----
__global__ __launch_bounds__(512) void bucket_fallback(
    const float* __restrict__ x, const float* __restrict__ w_qk,
    const float* __restrict__ b_qk, const float* __restrict__ R,
    const int* __restrict__ mlist, const int* __restrict__ mcount,
    int* __restrict__ buckets)
{
  __shared__ float qkrow[512];
  const int n = mcount[0];
  for (int ii = blockIdx.x; ii < n; ii += gridDim.x) {
    const int mm = mlist[ii];
    const int bh = mm >> 12, t = mm & 4095;
    const int b = bh >> 3, h = bh & 7;
    const float* xr = x + ((size_t)b * 4096 + t) * 512;
    {
      const int c = threadIdx.x;
      float a0 = 0.f;
      for (int f = 0; f < 512; ++f) a0 = fmaf(xr[f], w_qk[(size_t)f * 512 + c], a0);
      qkrow[c] = a0 + b_qk[c];
    }
    __syncthreads();
    if (threadIdx.x < 32) {
      const int col = h * 32 + threadIdx.x;
      float a0 = 0.f;
      for (int f = 0; f < 512; ++f) a0 = fmaf(qkrow[f], R[(size_t)f * 256 + col], a0);
      float m1; int i1;
      if (a0 >= 0.f) { m1 = a0;  i1 = threadIdx.x; }
      else           { m1 = -a0; i1 = threadIdx.x + 32; }
      #pragma unroll
      for (int off = 16; off; off >>= 1) {
        const float om = __shfl_xor(m1, off);
        const int   oi = __shfl_xor(i1, off);
        if (om > m1 || (om == m1 && oi < i1)) { m1 = om; i1 = oi; }
      }
      if (threadIdx.x == 0) buckets[(size_t)bh * 4096 + t] = i1;
    }
    __syncthreads();
  }
}

// -------- stable counting sort per (b,h), wave-parallel via 6-ballot match --------
// chunk = 64 consecutive tokens (one per lane). Stability: lane order within
// chunk = token order; chunk-major prefix preserves cross-chunk order.
__global__ __launch_bounds__(256) void sort_kernel(
    const int* __restrict__ buckets, int* __restrict__ st)
{
  __shared__ int bk_lds[4096];
  __shared__ int cnt[64][64];    // [chunk][bucket]: count, then exclusive offset
  __shared__ int bstart[64];
  const int tid = threadIdx.x;
  const int base = blockIdx.x * 4096;     // blockIdx = b*8+h
  const int wave = tid >> 6, lane = tid & 63;
  const unsigned long long lt = (1ull << lane) - 1ull;

  for (int t = tid; t < 4096; t += 256) bk_lds[t] = buckets[base + t];
  for (int i = tid; i < 4096; i += 256) ((int*)cnt)[i] = 0;
  __syncthreads();

  // phase 1: per-chunk histogram via ballot-match
  for (int c = wave; c < 64; c += 4) {
    const int bk = bk_lds[c * 64 + lane];
    unsigned long long mask = ~0ull;
    #pragma unroll
    for (int bit = 0; bit < 6; ++bit) {
      const unsigned long long bb = __ballot((bk >> bit) & 1);
      mask &= ((bk >> bit) & 1) ? bb : ~bb;
    }
    if ((mask & lt) == 0)                 // leader of this bucket's group
      cnt[c][bk] = __popcll(mask);
  }
  __syncthreads();

  // phase 2: per-bucket running prefix over chunks + bucket starts
  if (tid < 64) {
    int run = 0;
    for (int c = 0; c < 64; ++c) {
      const int v = cnt[c][tid];
      cnt[c][tid] = run;
      run += v;
    }
    int ex = run;                          // inclusive scan over buckets
    #pragma unroll
    for (int off = 1; off < 64; off <<= 1) {
      const int nn = __shfl_up(ex, off);
      if (lane >= off) ex += nn;
    }
    bstart[tid] = ex - run;                // exclusive
  }
  __syncthreads();

  // phase 3: stable scatter
  for (int c = wave; c < 64; c += 4) {
    const int tok = c * 64 + lane;
    const int bk = bk_lds[tok];
    unsigned long long mask = ~0ull;
    #pragma unroll
    for (int bit = 0; bit < 6; ++bit) {
      const unsigned long long bb = __ballot((bk >> bit) & 1);
      mask &= ((bk >> bit) & 1) ? bb : ~bb;
    }
    const int rank = (int)__popcll(mask & lt);
    st[base + bstart[bk] + cnt[c][bk] + rank] = tok;
  }
}

// -------- MFMA chunked attention: round-7 buffers + T14 stage-ahead --------
__global__ __launch_bounds__(256, 2) void attn_mfma(
    const ushort_t* __restrict__ qk_b, const ushort_t* __restrict__ v_b,
    const float* __restrict__ scale, const int* __restrict__ st,
    ushort_t* __restrict__ so, int g, int hbase)
{
  __shared__ __align__(16) char Q[32768];
  __shared__ __align__(16) char VT[32768];
  __shared__ __align__(16) char P[8192];
  __shared__ int   stt[64];
  __shared__ float scl[64];

  const int blk = blockIdx.x;
  const int cpg = g * 64;
  const int b = blk / cpg, rem = blk % cpg;
  const int hl = rem >> 6, c = rem & 63;
  const int tid = threadIdx.x, w = tid >> 6, l = tid & 63;
  const int m = l & 15, gq = l >> 4;
  const int srow = tid >> 5, su = tid & 31;

  if (tid < 64) {
    const int s = st[(size_t)((b * 8 + hbase + hl) * 4096) + c * 64 + tid];
    stt[tid] = s;
    scl[tid] = scale[b * 4096 + s];
  }
  __syncthreads();

  const size_t qkbase = (size_t)b * 4096;
  uint4 rg[8];

#define LOADG(SRC, HALF) { \
    _Pragma("unroll") \
    for (int it = 0; it < 8; ++it) { \
      const int row = it * 8 + srow; \
      rg[it] = *(const uint4*)((SRC) + (qkbase + stt[row]) * 512 + (HALF) * 256 + su * 8); \
    } }
#define WRITEQ() { \
    _Pragma("unroll") \
    for (int it = 0; it < 8; ++it) { \
      const int row = it * 8 + srow; \
      *(uint4*)(Q + ((row * 512 + su * 16) ^ ((row & 7) << 4))) = rg[it]; \
    } }
#define WRITEVT() { \
    _Pragma("unroll") \
    for (int it = 0; it < 8; ++it) { \
      const int j = it * 8 + srow; \
      const ushort_t* e = (const ushort_t*)&rg[it]; \
      _Pragma("unroll") \
      for (int ee = 0; ee < 8; ++ee) { \
        const int d = su * 8 + ee; \
        *(ushort_t*)(VT + ((d * 128 + j * 2) ^ (((d ^ (d >> 3)) & 7) << 4))) = e[ee]; \
      } \
    } }
#define COMPUTE_S() { \
    _Pragma("unroll") \
    for (int kf = 0; kf < 8; ++kf) { \
      const int arow = w * 16 + m; \
      const short8 af = *(const short8*)(Q + ((arow * 512 + kf * 64 + gq * 16) ^ ((arow & 7) << 4))); \
      _Pragma("unroll") \
      for (int jt = 0; jt < 4; ++jt) { \
        const int brow = jt * 16 + m; \
        const short8 bf = *(const short8*)(Q + ((brow * 512 + kf * 64 + gq * 16) ^ ((brow & 7) << 4))); \
        accS[jt] = __builtin_amdgcn_mfma_f32_16x16x32_bf16(af, bf, accS[jt], 0, 0, 0); \
      } \
    } }
#define COMPUTE_PV(ACCO) { \
    _Pragma("unroll") \
    for (int dt = 0; dt < 16; ++dt) { \
      _Pragma("unroll") \
      for (int kf = 0; kf < 2; ++kf) { \
        const int d = dt * 16 + m; \
        const short8 bv = *(const short8*)(VT + ((d * 128 + kf * 64 + gq * 16) ^ (((d ^ (d >> 3)) & 7) << 4))); \
        ACCO[dt] = __builtin_amdgcn_mfma_f32_16x16x32_bf16(ap[kf], bv, ACCO[dt], 0, 0, 0); \
      } \
    } }
#define BOUNCE(ACCO) { \
    _Pragma("unroll") \
    for (int dt = 0; dt < 16; ++dt) \
      _Pragma("unroll") \
      for (int r = 0; r < 4; ++r) { \
        const int i = w * 16 + gq * 4 + r; \
        const int dcol = dt * 16 + m; \
        *(ushort_t*)(Q + ((i * 512 + dcol * 2) ^ ((i & 7) << 4))) = f2b(ACCO[dt][r]); \
      } }
#define FLUSH(HALF) { \
    _Pragma("unroll") \
    for (int it = 0; it < 8; ++it) { \
      const int row = it * 8 + srow; \
      const uint4 dat = *(const uint4*)(Q + ((row * 512 + su * 16) ^ ((row & 7) << 4))); \
      *(uint4*)(so + (sobase + stt[row]) * 512 + (HALF) * 256 + su * 8) = dat; \
    } }

  f32x4 accS[4] = {};

  LOADG(qk_b, 0)
  WRITEQ()
  __syncthreads();
  LOADG(qk_b, 1)
  COMPUTE_S()
  __syncthreads();
  WRITEQ()
  __syncthreads();
  LOADG(v_b, 0)
  COMPUTE_S()
  __syncthreads();

  #pragma unroll
  for (int jt = 0; jt < 4; ++jt)
    #pragma unroll
    for (int r = 0; r < 4; ++r) {
      const int i = w * 16 + gq * 4 + r;
      const int j = jt * 16 + m;
      *(ushort_t*)(P + ((i * 128 + j * 2) ^ ((i & 7) << 4))) = f2b(accS[jt][r] * scl[j]);
    }
  WRITEVT()
  __syncthreads();

  const size_t sobase = (size_t)(b * g + hl) * 4096;
  LOADG(v_b, 1)
  short8 ap[2];
  #pragma unroll
  for (int kf = 0; kf < 2; ++kf) {
    const int i = w * 16 + m;
    ap[kf] = *(const short8*)(P + ((i * 128 + kf * 64 + gq * 16) ^ ((i & 7) << 4)));
  }
  f32x4 accO[16] = {};
  COMPUTE_PV(accO)
  __syncthreads();

  WRITEVT()
  BOUNCE(accO)
  __syncthreads();

  FLUSH(0)
  f32x4 accO2[16] = {};
  COMPUTE_PV(accO2)
  __syncthreads();

  BOUNCE(accO2)
  __syncthreads();
  FLUSH(1)

#undef LOADG
#undef WRITEQ
#undef WRITEVT
#undef COMPUTE_S
#undef COMPUTE_PV
#undef BOUNCE
#undef FLUSH
}

// -------- gather: o_b[tok][:] (+)= sum_{hl<g} so[(b*g+hl)*4096 + t][:], bf16 --------
__global__ __launch_bounds__(256) void gather_kernel(
    const ushort_t* __restrict__ so, ushort_t* __restrict__ o_b, int g, int first)
{
  const int tok = blockIdx.x;
  const int b = tok >> 12, t = tok & 4095;
  const int d0 = threadIdx.x * 2;
  ushort_t* dst = o_b + (size_t)tok * 512 + d0;
  float ax = 0.f, ay = 0.f;
  if (!first) {
    const unsigned u = *(const unsigned*)dst;
    ax = b2f(u & 0xffffu); ay = b2f(u >> 16);
  }
  const size_t stride = (size_t)4096 * 512;
  const ushort_t* src = so + ((size_t)(b * g) * 4096 + t) * 512 + d0;
  for (int hlp = 0; hlp < g; ++hlp) {
    const unsigned u = *(const unsigned*)src;
    ax += b2f(u & 0xffffu);
    ay += b2f(u >> 16);
    src += stride;
  }
  *(unsigned*)dst = ((unsigned)f2b(ay) << 16) | (unsigned)f2b(ax);
}

extern "C" void kernel_launch(void* const* d_in, const int* in_sizes, int n_in,
                              void* d_out, int out_size, void* d_ws, size_t ws_size,
                              hipStream_t stream) {
  const float* x         = (const float*)d_in[0];
  const float* rotations = (const float*)d_in[1];
  const float* w_qk      = (const float*)d_in[2];
  const float* b_qk      = (const float*)d_in[3];
  const float* w_v       = (const float*)d_in[4];
  const float* b_v       = (const float*)d_in[5];
  const float* w_out     = (const float*)d_in[6];
  const float* b_out     = (const float*)d_in[7];
  float* out = (float*)d_out;
  char* ws = (char*)d_ws;

  ushort_t* xh      = (ushort_t*)(ws);                  // 16.78 MB
  ushort_t* xl      = (ushort_t*)(ws + 16777216);       // 16.78 MB
  ushort_t* qk_hi   = (ushort_t*)(ws + 33554432);       // 16.78 MB
  ushort_t* v_b     = (ushort_t*)(ws + 50331648);       // 16.78 MB
  float*    rot     = (float*)(ws + 67108864);          // 16.78 MB (dead after fallback)
  ushort_t* o_b     = (ushort_t*)(ws + 67108864);       // alias: lives after gather
  ushort_t* wqkTh   = (ushort_t*)(ws + 83886080);       // 512 KB
  ushort_t* wvT     = (ushort_t*)(ws + 84410368);       // 512 KB
  ushort_t* woT     = (ushort_t*)(ws + 84934656);       // 512 KB
  ushort_t* W2Th    = (ushort_t*)(ws + 85458944);       // 256 KB
  ushort_t* W2Tl    = (ushort_t*)(ws + 85721088);       // 256 KB
  float*    b2      = (float*)(ws + 85983232);          // 1 KB (pad to 4K)
  float*    scale   = (float*)(ws + 85987328);          // 64 KB
  int*      buckets = (int*)(ws + 86052864);            // 512 KB
  int*      st      = (int*)(ws + 86577152);            // 512 KB
  int*      mlist   = (int*)(ws + 87101440);            // 512 KB (cap 131072: can't overflow)
  int*      mcount  = (int*)(ws + 87625728);            // 4 KB
  ushort_t* so      = (ushort_t*)(ws + 87629824);       // g * 16.78 MB
  const size_t so_off = 87629824;

  int g = 1;
  for (int cand = 8; cand >= 1; cand >>= 1)
    if (so_off + (size_t)cand * 16777216ull <= ws_size) { g = cand; break; }

  const dim3 blk256(256);
  hipLaunchKernelGGL(prep_kernel, dim3(5377), blk256, 0, stream,
                     x, w_qk, b_qk, rotations, w_v, w_out,
                     xh, xl, wqkTh, wvT, woT, W2Th, W2Tl, b2, mcount);

  hipLaunchKernelGGL(gemm_mfma_x2, dim3(128, 4), blk256, 0, stream, xh, xl, wqkTh, b_qk, qk_hi);
  hipLaunchKernelGGL(gemm_mfma, dim3(128, 4), blk256, 0, stream, xh, wvT, b_v, (float*)0, v_b, 1);
  hipLaunchKernelGGL(rot3_mfma, dim3(128, 2), blk256, 0, stream, xh, xl, W2Th, W2Tl, b2, rot);

  hipLaunchKernelGGL(argmax_scale, dim3(20480), blk256, 0, stream,
                     rot, buckets, mlist, mcount, 1.5e-3f, qk_hi, scale);
  hipLaunchKernelGGL(bucket_fallback, dim3(1024), dim3(512), 0, stream,
                     x, w_qk, b_qk, rotations, mlist, mcount, buckets);
  hipLaunchKernelGGL(sort_kernel, dim3(32), blk256, 0, stream, buckets, st);

  const int passes = 8 / g;
  for (int p = 0; p < passes; ++p) {
    const int hbase = p * g;
    hipLaunchKernelGGL(attn_mfma, dim3(4 * g * 64), blk256, 0, stream,
                       qk_hi, v_b, scale, st, so, g, hbase);
    hipLaunchKernelGGL(gather_kernel, dim3(16384), blk256, 0, stream,
                       so, o_b, g, (p == 0) ? 1 : 0);
  }

  hipLaunchKernelGGL(gemm_mfma, dim3(128, 4), blk256, 0, stream, o_b, woT, b_out, out, (ushort_t*)0, 0);
}

// Round 13
// 244.931 us; speedup vs baseline: 1.7047x; 1.0474x over previous
//
#include <hip/hip_runtime.h>

// LSH attention, B=4, T=4096, D=512, H=8 hashes, 64 buckets/hash, bucket size 64.
// Round 13: (a) qk GEMM reduced to 1 product (xl term dropped: its ~0.002
// contribution == bf16 rounding step) and fused with v GEMM into one launch
// (grid 128x8, shared A panels); (b) qk|v interleaved per token (2KB rows) for
// gather locality in attn. Everything else identical to round 12.

typedef __attribute__((ext_vector_type(8))) short short8;
typedef __attribute__((ext_vector_type(4))) float f32x4;
typedef unsigned short ushort_t;

__device__ __forceinline__ ushort_t f2b(float f) {
  union { float f; unsigned u; } x; x.f = f;
  unsigned r = x.u + 0x7fffu + ((x.u >> 16) & 1u);
  return (ushort_t)(r >> 16);
}
__device__ __forceinline__ float b2f(unsigned b) {
  union { unsigned u; float f; } x; x.u = b << 16;
  return x.f;
}
__device__ __forceinline__ void gload16(void* lds, const void* gp) {
  __builtin_amdgcn_global_load_lds(
      (const __attribute__((address_space(1))) unsigned int*)gp,
      (__attribute__((address_space(3))) unsigned int*)lds, 16, 0, 0);
}

// -------- fused prep: split_x | transpose_cvt x3 | w2_split | mcount=0 --------
__global__ __launch_bounds__(256) void prep_kernel(
    const float* __restrict__ x, const float* __restrict__ w_qk,
    const float* __restrict__ b_qk, const float* __restrict__ R,
    const float* __restrict__ w_v, const float* __restrict__ w_out,
    ushort_t* __restrict__ xh, ushort_t* __restrict__ xl,
    ushort_t* __restrict__ wqkT, ushort_t* __restrict__ wvT, ushort_t* __restrict__ woT,
    ushort_t* __restrict__ W2Th, ushort_t* __restrict__ W2Tl, float* __restrict__ b2,
    int* __restrict__ mcount)
{
  __shared__ float t[32][33];
  __shared__ float wrow[512];
  const int blk = blockIdx.x, tid = threadIdx.x;
  if (blk == 0 && tid == 0) mcount[0] = 0;

  if (blk < 4096) {                      // ---- split_x ----
    const int i = blk * 256 + tid;
    const float4 a = *(const float4*)(x + (size_t)i * 8);
    const float4 c = *(const float4*)(x + (size_t)i * 8 + 4);
    float v[8] = { a.x, a.y, a.z, a.w, c.x, c.y, c.z, c.w };
    ushort_t hi[8], lo[8];
    #pragma unroll
    for (int k = 0; k < 8; ++k) {
      hi[k] = f2b(v[k]);
      lo[k] = f2b(v[k] - b2f(hi[k]));
    }
    *(uint4*)(xh + (size_t)i * 8) = *(const uint4*)hi;
    *(uint4*)(xl + (size_t)i * 8) = *(const uint4*)lo;
  } else if (blk < 4864) {               // ---- transpose_cvt x3 ----
    const int idx = blk - 4096;
    const int mat = idx >> 8, r = idx & 255;
    const float* W  = (mat == 0) ? w_qk : (mat == 1) ? w_v : w_out;
    ushort_t*   Wt  = (mat == 0) ? wqkT : (mat == 1) ? wvT : woT;
    const int bx = (r & 15) * 32, by = (r >> 4) * 32;
    const int tx = tid & 31, ty = tid >> 5;
    #pragma unroll
    for (int j = 0; j < 4; ++j)
      t[ty + j*8][tx] = W[(size_t)(by + ty + j*8) * 512 + bx + tx];
    __syncthreads();
    #pragma unroll
    for (int j = 0; j < 4; ++j)
      Wt[(size_t)(bx + ty + j*8) * 512 + by + tx] = f2b(t[tx][ty + j*8]);
  } else {                               // ---- w2_split ----
    const int e = blk - 4864, j = tid;   // e in [0,513), j in [0,256)
    const float* src = (e < 512) ? (w_qk + (size_t)e * 512) : b_qk;
    wrow[j]       = src[j];
    wrow[j + 256] = src[j + 256];
    __syncthreads();
    float acc = 0.f;
    for (int f = 0; f < 512; ++f)
      acc = fmaf(wrow[f], R[(size_t)f * 256 + j], acc);
    if (e < 512) {
      const ushort_t hi = f2b(acc);
      W2Th[(size_t)j * 512 + e] = hi;
      W2Tl[(size_t)j * 512 + e] = f2b(acc - b2f(hi));
    } else {
      b2[j] = acc;
    }
  }
}

// ---- fused qk+v GEMM (1 product each), dbuf stage-ahead; out -> interleaved qkv ----
// grid (128, 8): y<4 -> qk col-block y; y>=4 -> v col-block y-4.
__global__ __launch_bounds__(256, 2) void gemm_qkv(
    const ushort_t* __restrict__ A, const ushort_t* __restrict__ wqkT,
    const ushort_t* __restrict__ wvT, const float* __restrict__ b_qk,
    const float* __restrict__ b_v, ushort_t* __restrict__ qkv)
{
  __shared__ __align__(16) char Al[32768];   // 2 x 16KB
  __shared__ __align__(16) char Bl[32768];
  const int bm = blockIdx.x * 128;
  const int sel = blockIdx.y >> 2;           // 0 = qk, 1 = v
  const int bn = (blockIdx.y & 3) * 128;
  const ushort_t* Wt   = sel ? wvT : wqkT;
  const float*    bias = sel ? b_v : b_qk;
  const int coff = sel * 512;
  const int tid = threadIdx.x, w = tid >> 6, l = tid & 63;
  const int m = l & 15, gq = l >> 4;
  f32x4 acc[2][8] = {};

#define STAGE1(NB, K0) { \
    _Pragma("unroll") \
    for (int j = 0; j < 4; ++j) { \
      const int row = w * 32 + j * 8 + (l >> 3); \
      const int ch = (l & 7) ^ (row & 7); \
      const int dst = (NB) * 16384 + w * 4096 + j * 1024 + l * 16; \
      gload16(Al + dst, A  + (size_t)(bm + row) * 512 + (K0) + ch * 8); \
      gload16(Bl + dst, Wt + (size_t)(bn + row) * 512 + (K0) + ch * 8); \
    } }

  STAGE1(0, 0)
  __syncthreads();
  for (int t = 0; t < 8; ++t) {
    const int cur = t & 1;
    if (t < 7) STAGE1(cur ^ 1, (t + 1) * 64)
    #pragma unroll
    for (int ks = 0; ks < 2; ++ks) {
      short8 bfr[8];
      #pragma unroll
      for (int tj = 0; tj < 8; ++tj) {
        const int brow = tj * 16 + m;
        bfr[tj] = *(const short8*)(Bl + cur * 16384 + ((brow * 128 + ks * 64 + gq * 16) ^ ((brow & 7) << 4)));
      }
      #pragma unroll
      for (int ti = 0; ti < 2; ++ti) {
        const int arow = w * 32 + ti * 16 + m;
        const short8 af = *(const short8*)(Al + cur * 16384 + ((arow * 128 + ks * 64 + gq * 16) ^ ((arow & 7) << 4)));
        #pragma unroll
        for (int tj = 0; tj < 8; ++tj)
          acc[ti][tj] = __builtin_amdgcn_mfma_f32_16x16x32_bf16(af, bfr[tj], acc[ti][tj], 0, 0, 0);
      }
    }
    __syncthreads();
  }
#undef STAGE1
  #pragma unroll
  for (int ti = 0; ti < 2; ++ti)
    #pragma unroll
    for (int tj = 0; tj < 8; ++tj) {
      const int col = bn + tj * 16 + m;
      const float bvv = bias[col];
      #pragma unroll
      for (int r2 = 0; r2 < 4; ++r2) {
        const int row = bm + w * 32 + ti * 16 + gq * 4 + r2;
        qkv[(size_t)row * 1024 + coff + col] = f2b(acc[ti][tj][r2] + bvv);
      }
    }
}

// ---- bf16 MFMA GEMM (1 product), dbuf; used for the out GEMM (fp32 out) ----
__global__ __launch_bounds__(256, 2) void gemm_mfma(
    const ushort_t* __restrict__ A, const ushort_t* __restrict__ Wt,
    const float* __restrict__ bias, float* __restrict__ Cf)
{
  __shared__ __align__(16) char Al[32768];
  __shared__ __align__(16) char Bl[32768];
  const int bm = blockIdx.x * 128, bn = blockIdx.y * 128;
  const int tid = threadIdx.x, w = tid >> 6, l = tid & 63;
  const int m = l & 15, gq = l >> 4;
  f32x4 acc[2][8] = {};

#define STAGE1(NB, K0) { \
    _Pragma("unroll") \
    for (int j = 0; j < 4; ++j) { \
      const int row = w * 32 + j * 8 + (l >> 3); \
      const int ch = (l & 7) ^ (row & 7); \
      const int dst = (NB) * 16384 + w * 4096 + j * 1024 + l * 16; \
      gload16(Al + dst, A  + (size_t)(bm + row) * 512 + (K0) + ch * 8); \
      gload16(Bl + dst, Wt + (size_t)(bn + row) * 512 + (K0) + ch * 8); \
    } }

  STAGE1(0, 0)
  __syncthreads();
  for (int t = 0; t < 8; ++t) {
    const int cur = t & 1;
    if (t < 7) STAGE1(cur ^ 1, (t + 1) * 64)
    #pragma unroll
    for (int ks = 0; ks < 2; ++ks) {
      short8 bfr[8];
      #pragma unroll
      for (int tj = 0; tj < 8; ++tj) {
        const int brow = tj * 16 + m;
        bfr[tj] = *(const short8*)(Bl + cur * 16384 + ((brow * 128 + ks * 64 + gq * 16) ^ ((brow & 7) << 4)));
      }
      #pragma unroll
      for (int ti = 0; ti < 2; ++ti) {
        const int arow = w * 32 + ti * 16 + m;
        const short8 af = *(const short8*)(Al + cur * 16384 + ((arow * 128 + ks * 64 + gq * 16) ^ ((arow & 7) << 4)));
        #pragma unroll
        for (int tj = 0; tj < 8; ++tj)
          acc[ti][tj] = __builtin_amdgcn_mfma_f32_16x16x32_bf16(af, bfr[tj], acc[ti][tj], 0, 0, 0);
      }
    }
    __syncthreads();
  }
#undef STAGE1
  #pragma unroll
  for (int ti = 0; ti < 2; ++ti)
    #pragma unroll
    for (int tj = 0; tj < 8; ++tj) {
      const int col = bn + tj * 16 + m;
      const float bvv = bias[col];
      #pragma unroll
      for (int r2 = 0; r2 < 4; ++r2) {
        const int row = bm + w * 32 + ti * 16 + gq * 4 + r2;
        Cf[(size_t)row * 512 + col] = acc[ti][tj][r2] + bvv;
      }
    }
}

// ---- rot = (xh+xl)@(W2h+W2l)^T + b2 via 3 MFMA products (lo*lo dropped), fp32 ----
__global__ __launch_bounds__(256, 2) void rot3_mfma(
    const ushort_t* __restrict__ Ah, const ushort_t* __restrict__ Al,
    const ushort_t* __restrict__ Bh, const ushort_t* __restrict__ Bl,
    const float* __restrict__ b2, float* __restrict__ rot)
{
  __shared__ __align__(16) char AH[16384], AL[16384], BH[16384], BL[16384];
  const int bm = blockIdx.x * 128, bn = blockIdx.y * 128;
  const int tid = threadIdx.x, w = tid >> 6, l = tid & 63;
  const int m = l & 15, gq = l >> 4;
  f32x4 acc[2][8] = {};
  for (int k0 = 0; k0 < 512; k0 += 64) {
    #pragma unroll
    for (int j = 0; j < 4; ++j) {
      const int row = w * 32 + j * 8 + (l >> 3);
      const int ch = (l & 7) ^ (row & 7);
      const int dst = w * 4096 + j * 1024 + l * 16;
      gload16(AH + dst, Ah + (size_t)(bm + row) * 512 + k0 + ch * 8);
      gload16(AL + dst, Al + (size_t)(bm + row) * 512 + k0 + ch * 8);
      gload16(BH + dst, Bh + (size_t)(bn + row) * 512 + k0 + ch * 8);
      gload16(BL + dst, Bl + (size_t)(bn + row) * 512 + k0 + ch * 8);
    }
    __syncthreads();
    #pragma unroll
    for (int ks = 0; ks < 2; ++ks) {
      short8 bh8[8], bl8[8];
      #pragma unroll
      for (int tj = 0; tj < 8; ++tj) {
        const int ba = ((tj * 16 + m) * 128 + ks * 64 + gq * 16) ^ (((tj * 16 + m) & 7) << 4);
        bh8[tj] = *(const short8*)(BH + ba);
        bl8[tj] = *(const short8*)(BL + ba);
      }
      #pragma unroll
      for (int ti = 0; ti < 2; ++ti) {
        const int arow = w * 32 + ti * 16 + m;
        const int aa = (arow * 128 + ks * 64 + gq * 16) ^ ((arow & 7) << 4);
        const short8 ah8 = *(const short8*)(AH + aa);
        const short8 al8 = *(const short8*)(AL + aa);
        #pragma unroll
        for (int tj = 0; tj < 8; ++tj) {
          acc[ti][tj] = __builtin_amdgcn_mfma_f32_16x16x32_bf16(ah8, bh8[tj], acc[ti][tj], 0, 0, 0);
          acc[ti][tj] = __builtin_amdgcn_mfma_f32_16x16x32_bf16(al8, bh8[tj], acc[ti][tj], 0, 0, 0);
          acc[ti][tj] = __builtin_amdgcn_mfma_f32_16x16x32_bf16(ah8, bl8[tj], acc[ti][tj], 0, 0, 0);
        }
      }
    }
    __syncthreads();
  }
  #pragma unroll
  for (int ti = 0; ti < 2; ++ti)
    #pragma unroll
    for (int tj = 0; tj < 8; ++tj) {
      const int col = bn + tj * 16 + m;
      const float bvv = b2[col];
      #pragma unroll
      for (int r2 = 0; r2 < 4; ++r2) {
        const int row = bm + w * 32 + ti * 16 + gq * 4 + r2;
        rot[(size_t)row * 256 + col] = acc[ti][tj][r2] + bvv;
      }
    }
}

// ---- fused: argmax+margin (blocks < 16384) | scale (blocks >= 16384) ----
__global__ __launch_bounds__(256) void argmax_scale(
    const float* __restrict__ rot, int* __restrict__ buckets,
    int* __restrict__ mlist, int* __restrict__ mcount, float tau,
    const ushort_t* __restrict__ qkv, float* __restrict__ scale)
{
  const int blk = blockIdx.x;
  if (blk < 16384) {
    const int tok = blk;
    const int j = threadIdx.x;             // j = h*32 + i
    const float r = rot[(size_t)tok * 256 + j];
    float m1, m2; int i1;
    if (r >= 0.f) { m1 = r;  i1 = j & 31;        m2 = -r; }
    else          { m1 = -r; i1 = (j & 31) + 32; m2 = r;  }
    #pragma unroll
    for (int off = 16; off; off >>= 1) {
      const float om1 = __shfl_xor(m1, off);
      const int   oi1 = __shfl_xor(i1, off);
      const float om2 = __shfl_xor(m2, off);
      float loser;
      if (om1 > m1 || (om1 == m1 && oi1 < i1)) { loser = m1; m1 = om1; i1 = oi1; }
      else loser = om1;
      m2 = fmaxf(fmaxf(m2, om2), loser);
    }
    if ((j & 31) == 0) {
      const int h = j >> 5, b = tok >> 12, t = tok & 4095;
      buckets[((b << 3) + h) * 4096 + t] = i1;
      if (m1 - m2 < tau) {
        const int k = atomicAdd(mcount, 1);
        mlist[k] = (((b << 3) + h) << 12) | t;
      }
    }
  } else {
    const int wave = threadIdx.x >> 6, lane = threadIdx.x & 63;
    const int tok = (blk - 16384) * 4 + wave;
    const uint4 H = *(const uint4*)(qkv + (size_t)tok * 1024 + lane * 8);
    const unsigned* hp = (const unsigned*)&H;
    float s = 0.f;
    #pragma unroll
    for (int e = 0; e < 4; ++e) {
      const float v0 = b2f(hp[e] & 0xffffu);
      const float v1 = b2f(hp[e] >> 16);
      s += v0 * v0 + v1 * v1;
    }
    #pragma unroll
    for (int off = 32; off; off >>= 1) s += __shfl_down(s, off);
    if (lane == 0) {
      const float nn = fmaxf(sqrtf(s), 1e-12f);
      scale[tok] = 0.044194173824159216f / nn;   // 512^-0.5 / norm
    }
  }
}

// ---- exact np-chain fallback for marginal (b,h,t) pairs ----
__global__ __launch_bounds__(512) void bucket_fallback(
    const float* __restrict__ x, const float* __restrict__ w_qk,
    const float* __restrict__ b_qk, const float* __restrict__ R,
    const int* __restrict__ mlist, const int* __restrict__ mcount,
    int* __restrict__ buckets)
{
  __shared__ float qkrow[512];
  const int n = mcount[0];
  for (int ii = blockIdx.x; ii < n; ii += gridDim.x) {
    const int mm = mlist[ii];
    const int bh = mm >> 12, t = mm & 4095;
    const int b = bh >> 3, h = bh & 7;
    const float* xr = x + ((size_t)b * 4096 + t) * 512;
    {
      const int c = threadIdx.x;
      float a0 = 0.f;
      for (int f = 0; f < 512; ++f) a0 = fmaf(xr[f], w_qk[(size_t)f * 512 + c], a0);
      qkrow[c] = a0 + b_qk[c];
    }
    __syncthreads();
    if (threadIdx.x < 32) {
      const int col = h * 32 + threadIdx.x;
      float a0 = 0.f;
      for (int f = 0; f < 512; ++f) a0 = fmaf(qkrow[f], R[(size_t)f * 256 + col], a0);
      float m1; int i1;
      if (a0 >= 0.f) { m1 = a0;  i1 = threadIdx.x; }
      else           { m1 = -a0; i1 = threadIdx.x + 32; }
      #pragma unroll
      for (int off = 16; off; off >>= 1) {
        const float om = __shfl_xor(m1, off);
        const int   oi = __shfl_xor(i1, off);
        if (om > m1 || (om == m1 && oi < i1)) { m1 = om; i1 = oi; }
      }
      if (threadIdx.x == 0) buckets[(size_t)bh * 4096 + t] = i1;
    }
    __syncthreads();
  }
}

// -------- stable counting sort per (b,h), wave-parallel via 6-ballot match --------
__global__ __launch_bounds__(256) void sort_kernel(
    const int* __restrict__ buckets, int* __restrict__ st)
{
  __shared__ int bk_lds[4096];
  __shared__ int cnt[64][64];
  __shared__ int bstart[64];
  const int tid = threadIdx.x;
  const int base = blockIdx.x * 4096;     // blockIdx = b*8+h
  const int wave = tid >> 6, lane = tid & 63;
  const unsigned long long lt = (1ull << lane) - 1ull;

  for (int t = tid; t < 4096; t += 256) bk_lds[t] = buckets[base + t];
  for (int i = tid; i < 4096; i += 256) ((int*)cnt)[i] = 0;
  __syncthreads();

  for (int c = wave; c < 64; c += 4) {
    const int bk = bk_lds[c * 64 + lane];
    unsigned long long mask = ~0ull;
    #pragma unroll
    for (int bit = 0; bit < 6; ++bit) {
      const unsigned long long bb = __ballot((bk >> bit) & 1);
      mask &= ((bk >> bit) & 1) ? bb : ~bb;
    }
    if ((mask & lt) == 0)
      cnt[c][bk] = __popcll(mask);
  }
  __syncthreads();

  if (tid < 64) {
    int run = 0;
    for (int c = 0; c < 64; ++c) {
      const int v = cnt[c][tid];
      cnt[c][tid] = run;
      run += v;
    }
    int ex = run;
    #pragma unroll
    for (int off = 1; off < 64; off <<= 1) {
      const int nn = __shfl_up(ex, off);
      if (lane >= off) ex += nn;
    }
    bstart[tid] = ex - run;
  }
  __syncthreads();

  for (int c = wave; c < 64; c += 4) {
    const int tok = c * 64 + lane;
    const int bk = bk_lds[tok];
    unsigned long long mask = ~0ull;
    #pragma unroll
    for (int bit = 0; bit < 6; ++bit) {
      const unsigned long long bb = __ballot((bk >> bit) & 1);
      mask &= ((bk >> bit) & 1) ? bb : ~bb;
    }
    const int rank = (int)__popcll(mask & lt);
    st[base + bstart[bk] + cnt[c][bk] + rank] = tok;
  }
}

// -------- MFMA chunked attention: interleaved qkv input, T14 stage-ahead --------
__global__ __launch_bounds__(256, 2) void attn_mfma(
    const ushort_t* __restrict__ qkv, const float* __restrict__ scale,
    const int* __restrict__ st, ushort_t* __restrict__ so, int g, int hbase)
{
  __shared__ __align__(16) char Q[32768];
  __shared__ __align__(16) char VT[32768];
  __shared__ __align__(16) char P[8192];
  __shared__ int   stt[64];
  __shared__ float scl[64];

  const int blk = blockIdx.x;
  const int cpg = g * 64;
  const int b = blk / cpg, rem = blk % cpg;
  const int hl = rem >> 6, c = rem & 63;
  const int tid = threadIdx.x, w = tid >> 6, l = tid & 63;
  const int m = l & 15, gq = l >> 4;
  const int srow = tid >> 5, su = tid & 31;

  if (tid < 64) {
    const int s = st[(size_t)((b * 8 + hbase + hl) * 4096) + c * 64 + tid];
    stt[tid] = s;
    scl[tid] = scale[b * 4096 + s];
  }
  __syncthreads();

  const size_t qkbase = (size_t)b * 4096;
  uint4 rg[8];

#define LOADG(VOFF, HALF) { \
    _Pragma("unroll") \
    for (int it = 0; it < 8; ++it) { \
      const int row = it * 8 + srow; \
      rg[it] = *(const uint4*)(qkv + (qkbase + stt[row]) * 1024 + (VOFF) + (HALF) * 256 + su * 8); \
    } }
#define WRITEQ() { \
    _Pragma("unroll") \
    for (int it = 0; it < 8; ++it) { \
      const int row = it * 8 + srow; \
      *(uint4*)(Q + ((row * 512 + su * 16) ^ ((row & 7) << 4))) = rg[it]; \
    } }
#define WRITEVT() { \
    _Pragma("unroll") \
    for (int it = 0; it < 8; ++it) { \
      const int j = it * 8 + srow; \
      const ushort_t* e = (const ushort_t*)&rg[it]; \
      _Pragma("unroll") \
      for (int ee = 0; ee < 8; ++ee) { \
        const int d = su * 8 + ee; \
        *(ushort_t*)(VT + ((d * 128 + j * 2) ^ (((d ^ (d >> 3)) & 7) << 4))) = e[ee]; \
      } \
    } }
#define COMPUTE_S() { \
    _Pragma("unroll") \
    for (int kf = 0; kf < 8; ++kf) { \
      const int arow = w * 16 + m; \
      const short8 af = *(const short8*)(Q + ((arow * 512 + kf * 64 + gq * 16) ^ ((arow & 7) << 4))); \
      _Pragma("unroll") \
      for (int jt = 0; jt < 4; ++jt) { \
        const int brow = jt * 16 + m; \
        const short8 bf = *(const short8*)(Q + ((brow * 512 + kf * 64 + gq * 16) ^ ((brow & 7) << 4))); \
        accS[jt] = __builtin_amdgcn_mfma_f32_16x16x32_bf16(af, bf, accS[jt], 0, 0, 0); \
      } \
    } }
#define COMPUTE_PV(ACCO) { \
    _Pragma("unroll") \
    for (int dt = 0; dt < 16; ++dt) { \
      _Pragma("unroll") \
      for (int kf = 0; kf < 2; ++kf) { \
        const int d = dt * 16 + m; \
        const short8 bv = *(const short8*)(VT + ((d * 128 + kf * 64 + gq * 16) ^ (((d ^ (d >> 3)) & 7) << 4))); \
        ACCO[dt] = __builtin_amdgcn_mfma_f32_16x16x32_bf16(ap[kf], bv, ACCO[dt], 0, 0, 0); \
      } \
    } }
#define BOUNCE(ACCO) { \
    _Pragma("unroll") \
    for (int dt = 0; dt < 16; ++dt) \
      _Pragma("unroll") \
      for (int r = 0; r < 4; ++r) { \
        const int i = w * 16 + gq * 4 + r; \
        const int dcol = dt * 16 + m; \
        *(ushort_t*)(Q + ((i * 512 + dcol * 2) ^ ((i & 7) << 4))) = f2b(ACCO[dt][r]); \
      } }
#define FLUSH(HALF) { \
    _Pragma("unroll") \
    for (int it = 0; it < 8; ++it) { \
      const int row = it * 8 + srow; \
      const uint4 dat = *(const uint4*)(Q + ((row * 512 + su * 16) ^ ((row & 7) << 4))); \
      *(uint4*)(so + (sobase + stt[row]) * 512 + (HALF) * 256 + su * 8) = dat; \
    } }

  f32x4 accS[4] = {};

  LOADG(0, 0)
  WRITEQ()
  __syncthreads();
  LOADG(0, 1)
  COMPUTE_S()
  __syncthreads();
  WRITEQ()
  __syncthreads();
  LOADG(512, 0)
  COMPUTE_S()
  __syncthreads();

  #pragma unroll
  for (int jt = 0; jt < 4; ++jt)
    #pragma unroll
    for (int r = 0; r < 4; ++r) {
      const int i = w * 16 + gq * 4 + r;
      const int j = jt * 16 + m;
      *(ushort_t*)(P + ((i * 128 + j * 2) ^ ((i & 7) << 4))) = f2b(accS[jt][r] * scl[j]);
    }
  WRITEVT()
  __syncthreads();

  const size_t sobase = (size_t)(b * g + hl) * 4096;
  LOADG(512, 1)
  short8 ap[2];
  #pragma unroll
  for (int kf = 0; kf < 2; ++kf) {
    const int i = w * 16 + m;
    ap[kf] = *(const short8*)(P + ((i * 128 + kf * 64 + gq * 16) ^ ((i & 7) << 4)));
  }
  f32x4 accO[16] = {};
  COMPUTE_PV(accO)
  __syncthreads();

  WRITEVT()
  BOUNCE(accO)
  __syncthreads();

  FLUSH(0)
  f32x4 accO2[16] = {};
  COMPUTE_PV(accO2)
  __syncthreads();

  BOUNCE(accO2)
  __syncthreads();
  FLUSH(1)

#undef LOADG
#undef WRITEQ
#undef WRITEVT
#undef COMPUTE_S
#undef COMPUTE_PV
#undef BOUNCE
#undef FLUSH
}

// -------- gather: o_b[tok][:] (+)= sum_{hl<g} so[(b*g+hl)*4096 + t][:], bf16 --------
__global__ __launch_bounds__(256) void gather_kernel(
    const ushort_t* __restrict__ so, ushort_t* __restrict__ o_b, int g, int first)
{
  const int tok = blockIdx.x;
  const int b = tok >> 12, t = tok & 4095;
  const int d0 = threadIdx.x * 2;
  ushort_t* dst = o_b + (size_t)tok * 512 + d0;
  float ax = 0.f, ay = 0.f;
  if (!first) {
    const unsigned u = *(const unsigned*)dst;
    ax = b2f(u & 0xffffu); ay = b2f(u >> 16);
  }
  const size_t stride = (size_t)4096 * 512;
  const ushort_t* src = so + ((size_t)(b * g) * 4096 + t) * 512 + d0;
  for (int hlp = 0; hlp < g; ++hlp) {
    const unsigned u = *(const unsigned*)src;
    ax += b2f(u & 0xffffu);
    ay += b2f(u >> 16);
    src += stride;
  }
  *(unsigned*)dst = ((unsigned)f2b(ay) << 16) | (unsigned)f2b(ax);
}

extern "C" void kernel_launch(void* const* d_in, const int* in_sizes, int n_in,
                              void* d_out, int out_size, void* d_ws, size_t ws_size,
                              hipStream_t stream) {
  const float* x         = (const float*)d_in[0];
  const float* rotations = (const float*)d_in[1];
  const float* w_qk      = (const float*)d_in[2];
  const float* b_qk      = (const float*)d_in[3];
  const float* w_v       = (const float*)d_in[4];
  const float* b_v       = (const float*)d_in[5];
  const float* w_out     = (const float*)d_in[6];
  const float* b_out     = (const float*)d_in[7];
  float* out = (float*)d_out;
  char* ws = (char*)d_ws;

  ushort_t* xh      = (ushort_t*)(ws);                  // 16.78 MB
  ushort_t* xl      = (ushort_t*)(ws + 16777216);       // 16.78 MB
  ushort_t* qkv     = (ushort_t*)(ws + 33554432);       // 33.55 MB (qk|v interleaved, 2KB/token)
  float*    rot     = (float*)(ws + 67108864);          // 16.78 MB (dead after fallback)
  ushort_t* o_b     = (ushort_t*)(ws + 67108864);       // alias: lives after gather
  ushort_t* wqkTh   = (ushort_t*)(ws + 83886080);       // 512 KB
  ushort_t* wvT     = (ushort_t*)(ws + 84410368);       // 512 KB
  ushort_t* woT     = (ushort_t*)(ws + 84934656);       // 512 KB
  ushort_t* W2Th    = (ushort_t*)(ws + 85458944);       // 256 KB
  ushort_t* W2Tl    = (ushort_t*)(ws + 85721088);       // 256 KB
  float*    b2      = (float*)(ws + 85983232);          // 1 KB (pad to 4K)
  float*    scale   = (float*)(ws + 85987328);          // 64 KB
  int*      buckets = (int*)(ws + 86052864);            // 512 KB
  int*      st      = (int*)(ws + 86577152);            // 512 KB
  int*      mlist   = (int*)(ws + 87101440);            // 512 KB (cap 131072: can't overflow)
  int*      mcount  = (int*)(ws + 87625728);            // 4 KB
  ushort_t* so      = (ushort_t*)(ws + 87629824);       // g * 16.78 MB
  const size_t so_off = 87629824;

  int g = 1;
  for (int cand = 8; cand >= 1; cand >>= 1)
    if (so_off + (size_t)cand * 16777216ull <= ws_size) { g = cand; break; }

  const dim3 blk256(256);
  hipLaunchKernelGGL(prep_kernel, dim3(5377), blk256, 0, stream,
                     x, w_qk, b_qk, rotations, w_v, w_out,
                     xh, xl, wqkTh, wvT, woT, W2Th, W2Tl, b2, mcount);

  hipLaunchKernelGGL(gemm_qkv, dim3(128, 8), blk256, 0, stream, xh, wqkTh, wvT, b_qk, b_v, qkv);
  hipLaunchKernelGGL(rot3_mfma, dim3(128, 2), blk256, 0, stream, xh, xl, W2Th, W2Tl, b2, rot);

  hipLaunchKernelGGL(argmax_scale, dim3(20480), blk256, 0, stream,
                     rot, buckets, mlist, mcount, 1.5e-3f, qkv, scale);
  hipLaunchKernelGGL(bucket_fallback, dim3(1024), dim3(512), 0, stream,
                     x, w_qk, b_qk, rotations, mlist, mcount, buckets);
  hipLaunchKernelGGL(sort_kernel, dim3(32), blk256, 0, stream, buckets, st);

  const int passes = 8 / g;
  for (int p = 0; p < passes; ++p) {
    const int hbase = p * g;
    hipLaunchKernelGGL(attn_mfma, dim3(4 * g * 64), blk256, 0, stream,
                       qkv, scale, st, so, g, hbase);
    hipLaunchKernelGGL(gather_kernel, dim3(16384), blk256, 0, stream,
                       so, o_b, g, (p == 0) ? 1 : 0);
  }

  hipLaunchKernelGGL(gemm_mfma, dim3(128, 4), blk256, 0, stream, o_b, woT, b_out, out);
}